// Round 11
// baseline (514.837 us; speedup 1.0000x reference)
//
#include <hip/hip_runtime.h>

// GraphSAGE-pool ×3 + BN + classifier, bf16 activations + MFMA GEMMs.
// R24 = R23 with the BN transform moved from reg-staging to IN-LDS RMW:
//  R23's stageBN (global->reg->transform->ds_write) was software-pipelined
//  by the compiler (R18 mechanism): raw uint4s live across the MFMA block
//  -> VGPR 160, occ 8.3%, EPI3 = slowest dispatch (62us). Now Y1 halves are
//  staged RAW via global_load_lds (no data regs); after the existing
//  barrier each thread RMWs its own 4 staged uint4 LDS slots with the
//  identical f2bf(leaky(fmaf(bf2f(y),sc,sf))) chain (+1 barrier to
//  publish). LDS bits bit-identical to R23 -> output unchanged.
//  bn_finalize/bn_apply remain deleted (R22 win).

#define N_NODES 100000
#define N_EDGES 1000000
#define F 128
#define NEG_SLOPE 0.01f
#define BN_EPS 1e-5f

typedef __attribute__((ext_vector_type(8))) short bf16x8;
typedef __attribute__((ext_vector_type(4))) float f32x4;
typedef __attribute__((ext_vector_type(2))) unsigned short u16x2;

typedef __attribute__((address_space(3))) unsigned int as3_uint;
typedef __attribute__((address_space(1))) const unsigned int as1_cuint;

__device__ __forceinline__ void gload16(const void* g, void* l) {
    __builtin_amdgcn_global_load_lds((as1_cuint*)g, (as3_uint*)l, 16, 0, 0);
}

__device__ __forceinline__ unsigned short f2bf(float f) {
    unsigned int u = __float_as_uint(f);
    u += 0x7fff + ((u >> 16) & 1);          // RNE
    return (unsigned short)(u >> 16);
}
__device__ __forceinline__ float bf2f(unsigned short h) {
    return __uint_as_float(((unsigned int)h) << 16);
}

// ---------------- combined zero fill: deg (25000 f4) + stats (64 f4) ----------------
__global__ __launch_bounds__(256) void zero_misc_kernel(
    float4* __restrict__ deg4, float4* __restrict__ stats4)
{
    if (blockIdx.x < 98) {
        const int i = blockIdx.x * 256 + threadIdx.x;
        if (i < 25000) deg4[i] = make_float4(0.f, 0.f, 0.f, 0.f);
    } else {
        if (threadIdx.x < 64) stats4[threadIdx.x] = make_float4(0.f, 0.f, 0.f, 0.f);
    }
}

// ---------------- fused prep: f32->bf16 convert | degree hist(+rank) | weight pack ----
#define PREP_GROUPS 4483
__global__ __launch_bounds__(256) void prep_kernel(
    const float4* __restrict__ nf, uint2* __restrict__ xout,
    const int* __restrict__ dst, int* __restrict__ deg,
    unsigned short* __restrict__ erank,
    const float* __restrict__ w0, const float* __restrict__ w1, const float* __restrict__ w2,
    const float* __restrict__ w3, const float* __restrict__ w4, const float* __restrict__ w5,
    const float* __restrict__ w6, const float* __restrict__ w7, const float* __restrict__ w8,
    short* __restrict__ wp_p, short* __restrict__ wsn_p)
{
    const int g = blockIdx.x >> 2;
    const int k = blockIdx.x & 3;
    const int tid = threadIdx.x;
    if (k < 3) {
        // ---- fp32 -> bf16 convert ----
        const int c = g * 3 + k;
        if (c >= 12500) return;
        const long i = (long)c * 256 + tid;
        float4 v = nf[i];
        uint2 o;
        o.x = (unsigned)f2bf(v.x) | ((unsigned)f2bf(v.y) << 16);
        o.y = (unsigned)f2bf(v.z) | ((unsigned)f2bf(v.w) << 16);
        xout[i] = o;
        return;
    }
    if (g < 3907) {
        // ---- degree histogram; keep the return = edge's rank within dst node ----
        const int e = g * 256 + tid;
        if (e < N_EDGES) {
            const int d = __builtin_nontemporal_load(&dst[e]);
            erank[e] = (unsigned short)atomicAdd(&deg[d], 1);
        }
        return;
    }
    const int po = g - 3907;
    if (po >= 576) return;
    // ---- weight pack: f32 [128][128] -> bf16 frag-order [16][128][8] ----
    const int idx = po * 256 + tid;                 // 0 .. 147455
    const int matid = idx >> 14;                    // 0..8, block-uniform
    const int layer = (matid * 11) >> 5;            // /3
    const int mat = matid - 3 * layer;
    const int i = idx & 16383;
    const int kk = i >> 7, n = i & 127;
    const float* srcm;
    switch (matid) {
        case 0: srcm = w0; break; case 1: srcm = w1; break; case 2: srcm = w2; break;
        case 3: srcm = w3; break; case 4: srcm = w4; break; case 5: srcm = w5; break;
        case 6: srcm = w6; break; case 7: srcm = w7; break; default: srcm = w8; break;
    }
    const int slot = ((kk >> 3) * 128 + n) * 8 + (kk & 7);
    const short v = (short)f2bf(srcm[i]);
    if (mat == 0) wp_p[layer * 16384 + slot] = v;
    else wsn_p[layer * 32768 + (mat == 2 ? 16384 : 0) + slot] = v;
}

// ---------------- MFMA GEMM body, m97-style (R17); optional BN via in-LDS RMW ----
// BN: Y1 halves staged RAW (global_load_lds); after the staging barrier each
// thread RMWs its own 4 staged uint4 LDS slots (cols kbase+gchunk*8+e) with
// f2bf(leaky(fmaf(bf2f(y),sc,sf))) — identical chain to bn_apply.
template<int NKS, bool BN>
__device__ __forceinline__ void gemm_body(
    const int bid,
    const short* __restrict__ A1, const short* __restrict__ A2,
    const short* __restrict__ Bp, const float* __restrict__ bias,
    unsigned short* __restrict__ Cout, const int n_rows, const int act,
    const float* __restrict__ stats, const float* __restrict__ gamma,
    const float* __restrict__ beta)
{
    constexpr int S = NKS / 2;                   // BK=64 steps
    __shared__ short tile[2 * 8192];             // 2 x (128 rows x 64 cols); reused as epilogue bounce
    __shared__ float scS[BN ? 128 : 1];
    __shared__ float sfS[BN ? 128 : 1];

    const int tid = threadIdx.x;
    const int wave = tid >> 6;
    const int lane = tid & 63;
    const int m = lane & 15, q = lane >> 4;
    const int r0 = bid * 128;
    const int rw = (wave >> 1) * 64;             // wave row-quadrant offset
    const int r0q = r0 + rw;
    const int c0 = (wave & 1) * 64;
    const int gchunk = (tid & 7) ^ ((tid >> 3) & 7);

    if constexpr (BN) {
        if (tid < 128) {
            const float inv = 1.f / N_NODES;
            const float mean = stats[tid] * inv;
            const float var = stats[128 + tid] * inv - mean * mean;
            const float sc = gamma[tid] * rsqrtf(var + BN_EPS);
            scS[tid] = sc;
            sfS[tid] = fmaf(-mean, sc, beta[tid]);
        }
    }

    f32x4 acc[4][4];
#pragma unroll
    for (int i = 0; i < 4; ++i)
#pragma unroll
        for (int j = 0; j < 4; ++j)
#pragma unroll
            for (int r = 0; r < 4; ++r) acc[i][j][r] = 0.f;

    auto stage = [&](int s, int buf) {
        const short* Ap = (NKS == 8 && s >= 2) ? A2 : A1;
        const int kbase = (s & 1) * 64;          // shorts
#pragma unroll
        for (int p = 0; p < 4; ++p) {
            int row = r0 + (tid >> 3) + 32 * p;
            row = min(row, n_rows - 1);
            gload16(Ap + (size_t)row * F + kbase + gchunk * 8,
                    &tile[buf * 8192 + p * 2048 + tid * 8]);
        }
    };

    // in-LDS BN transform of this thread's own staged slots (after barrier)
    auto rmwBN = [&](int s, int buf) {
        const int kbase = (s & 1) * 64;
        float scv[8], sfv[8];
#pragma unroll
        for (int e = 0; e < 8; ++e) {
            scv[e] = scS[kbase + gchunk * 8 + e];
            sfv[e] = sfS[kbase + gchunk * 8 + e];
        }
#pragma unroll
        for (int p = 0; p < 4; ++p) {
            unsigned int* slot = (unsigned int*)&tile[buf * 8192 + p * 2048 + tid * 8];
            unsigned int w0v = slot[0], w1v = slot[1], w2v = slot[2], w3v = slot[3];
            const unsigned int w[4] = {w0v, w1v, w2v, w3v};
#pragma unroll
            for (int j = 0; j < 4; ++j) {
                float lo = fmaf(bf2f((unsigned short)(w[j] & 0xffffu)), scv[2 * j], sfv[2 * j]);
                float hi = fmaf(bf2f((unsigned short)(w[j] >> 16)), scv[2 * j + 1], sfv[2 * j + 1]);
                lo = lo > 0.f ? lo : lo * NEG_SLOPE;
                hi = hi > 0.f ? hi : hi * NEG_SLOPE;
                slot[j] = (unsigned)f2bf(lo) | ((unsigned)f2bf(hi) << 16);
            }
        }
    };

    stage(0, 0);
    __syncthreads();                             // buffer0 staged; scS/sfS visible
    if constexpr (BN) {
        rmwBN(0, 0);
        __syncthreads();
    }

    for (int s = 0; s < S; ++s) {
        if (s + 1 < S) stage(s + 1, (s + 1) & 1);
        const short* tb = &tile[(s & 1) * 8192];
#pragma unroll
        for (int ks2 = 0; ks2 < 2; ++ks2) {
            const int ks32 = s * 2 + ks2;
            bf16x8 b[4], a[4];
#pragma unroll
            for (int ni = 0; ni < 4; ++ni)
                b[ni] = *(const bf16x8*)(Bp + ((size_t)(ks32 * 4 + q) * F + c0 + ni * 16 + m) * 8);
#pragma unroll
            for (int mi = 0; mi < 4; ++mi)
                a[mi] = *(const bf16x8*)(tb + (rw + mi * 16 + m) * 64 + (((ks2 * 4 + q) ^ (m & 7)) << 3));
#pragma unroll
            for (int mi = 0; mi < 4; ++mi)
#pragma unroll
                for (int ni = 0; ni < 4; ++ni)
                    acc[mi][ni] = __builtin_amdgcn_mfma_f32_16x16x32_bf16(a[mi], b[ni], acc[mi][ni], 0, 0, 0);
        }
        __syncthreads();   // staged loads complete + tile reads done
        if (BN && s + 1 < S && (NKS == 4 || s + 1 < 2)) {
            rmwBN(s + 1, (s + 1) & 1);
            __syncthreads();
        }
    }

    float bv[4];
#pragma unroll
    for (int ni = 0; ni < 4; ++ni) bv[ni] = bias[c0 + ni * 16 + m];

    short* ep = &tile[wave * 1280];              // aliased onto dead A-tile buffer
    const int colc_lo = m >> 3, cin = m & 7;
#pragma unroll
    for (int mi = 0; mi < 4; ++mi) {
#pragma unroll
        for (int ni = 0; ni < 4; ++ni) {
            const int colc = 2 * ni + colc_lo;
#pragma unroll
            for (int rg = 0; rg < 4; ++rg) {
                const int row16 = q * 4 + rg;
                float v = acc[mi][ni][rg] + bv[ni];
                if (act == 1) v = v > 0.f ? v : 0.f;
                else if (act == 2) v = v > 0.f ? v : v * NEG_SLOPE;
                ep[row16 * 80 + ((colc ^ (row16 & 7)) << 3) + cin] = (short)f2bf(v);
            }
        }
        __syncthreads();
#pragma unroll
        for (int p = 0; p < 2; ++p) {
            const int lrow = (lane >> 3) + 8 * p;
            bf16x8 vv = *(const bf16x8*)&ep[lrow * 80 + (((lane & 7) ^ (lrow & 7)) << 3)];
            const int grow = r0q + mi * 16 + lrow;
            if (grow < n_rows)
                *(bf16x8*)(Cout + (size_t)grow * F + c0 + ((lane & 7) << 3)) = vv;
        }
        __syncthreads();
    }
}

// layer-2 fc_pool: hp2 = relu( bnleaky(Y1) @ Wp2 + bp2 ), BN via in-LDS RMW
__global__ __launch_bounds__(256) void gemm_mfma4_bn(
    const short* __restrict__ A1,
    const short* __restrict__ Bp, const float* __restrict__ bias,
    unsigned short* __restrict__ Cout, int n_rows, int act,
    const float* __restrict__ stats, const float* __restrict__ gamma,
    const float* __restrict__ beta)
{
    gemm_body<4, true>(blockIdx.x, A1, (const short*)nullptr, Bp, bias, Cout,
                       n_rows, act, stats, gamma, beta);
}

// ---------------- fused NKS=8 Y-GEMM (R17) with per-layer tail (EPI) ----------------
// EPI=1: +hp-GEMM (Y@Bp2+bias2, relu) -> Cout2;  Y stored to Cout.
// EPI=2: +BN stats partial accumulation into stats[]; Y stored to Cout.
// EPI=3: +classifier (Ytile@Wc+bc) -> out; Y NOT stored; BN in-LDS RMW on A1 halves.
template<int EPI>
__global__ __launch_bounds__(256) void gemm8_fused(
    const short* __restrict__ A1, const short* __restrict__ A2,
    const short* __restrict__ Bp, const float* __restrict__ bias,
    unsigned short* __restrict__ Cout,
    const short* __restrict__ Bp2, const float* __restrict__ bias2,
    unsigned short* __restrict__ Cout2,
    float* __restrict__ stats,
    const float* __restrict__ Wc, const float* __restrict__ bc,
    float* __restrict__ out,
    const float* __restrict__ gamma, const float* __restrict__ beta,
    int n_rows, int act)
{
    __shared__ short tile[2 * 8192];
    __shared__ float wcS[EPI == 3 ? 2064 : 4];   // 2048 Wc + 16 bc (EPI3 only)
    __shared__ float scS[EPI == 3 ? 128 : 1];
    __shared__ float sfS[EPI == 3 ? 128 : 1];

    const int tid = threadIdx.x;
    const int wave = tid >> 6;
    const int lane = tid & 63;
    const int m = lane & 15, q = lane >> 4;
    const int r0 = blockIdx.x * 128;
    const int rw = (wave >> 1) * 64;
    const int r0q = r0 + rw;
    const int c0 = (wave & 1) * 64;
    const int gchunk = (tid & 7) ^ ((tid >> 3) & 7);

    if constexpr (EPI == 3) {
        for (int i = tid; i < 2048; i += 256) wcS[i] = Wc[i];
        if (tid < 16) wcS[2048 + tid] = bc[tid];
        if (tid < 128) {
            const float inv = 1.f / N_NODES;
            const float mean = stats[tid] * inv;
            const float var = stats[128 + tid] * inv - mean * mean;
            const float sc = gamma[tid] * rsqrtf(var + BN_EPS);
            scS[tid] = sc;
            sfS[tid] = fmaf(-mean, sc, beta[tid]);
        }
    }

    f32x4 acc[4][4];
#pragma unroll
    for (int i = 0; i < 4; ++i)
#pragma unroll
        for (int j = 0; j < 4; ++j)
#pragma unroll
            for (int r = 0; r < 4; ++r) acc[i][j][r] = 0.f;

    auto stage = [&](int s, int buf) {
        const short* Ap = (s >= 2) ? A2 : A1;
        const int kbase = (s & 1) * 64;
#pragma unroll
        for (int p = 0; p < 4; ++p) {
            int row = r0 + (tid >> 3) + 32 * p;
            row = min(row, n_rows - 1);
            gload16(Ap + (size_t)row * F + kbase + gchunk * 8,
                    &tile[buf * 8192 + p * 2048 + tid * 8]);
        }
    };

    auto rmwBN = [&](int s, int buf) {
        const int kbase = (s & 1) * 64;
        float scv[8], sfv[8];
#pragma unroll
        for (int e = 0; e < 8; ++e) {
            scv[e] = scS[kbase + gchunk * 8 + e];
            sfv[e] = sfS[kbase + gchunk * 8 + e];
        }
#pragma unroll
        for (int p = 0; p < 4; ++p) {
            unsigned int* slot = (unsigned int*)&tile[buf * 8192 + p * 2048 + tid * 8];
            unsigned int w0v = slot[0], w1v = slot[1], w2v = slot[2], w3v = slot[3];
            const unsigned int w[4] = {w0v, w1v, w2v, w3v};
#pragma unroll
            for (int j = 0; j < 4; ++j) {
                float lo = fmaf(bf2f((unsigned short)(w[j] & 0xffffu)), scv[2 * j], sfv[2 * j]);
                float hi = fmaf(bf2f((unsigned short)(w[j] >> 16)), scv[2 * j + 1], sfv[2 * j + 1]);
                lo = lo > 0.f ? lo : lo * NEG_SLOPE;
                hi = hi > 0.f ? hi : hi * NEG_SLOPE;
                slot[j] = (unsigned)f2bf(lo) | ((unsigned)f2bf(hi) << 16);
            }
        }
    };

    auto compute_step = [&](const short* __restrict__ Bpp, int s, f32x4 (&ac)[4][4]) {
        const short* tb = &tile[(s & 1) * 8192];
#pragma unroll
        for (int ks2 = 0; ks2 < 2; ++ks2) {
            const int ks32 = s * 2 + ks2;
            bf16x8 b[4], a[4];
#pragma unroll
            for (int ni = 0; ni < 4; ++ni)
                b[ni] = *(const bf16x8*)(Bpp + ((size_t)(ks32 * 4 + q) * F + c0 + ni * 16 + m) * 8);
#pragma unroll
            for (int mi = 0; mi < 4; ++mi)
                a[mi] = *(const bf16x8*)(tb + (rw + mi * 16 + m) * 64 + (((ks2 * 4 + q) ^ (m & 7)) << 3));
#pragma unroll
            for (int mi = 0; mi < 4; ++mi)
#pragma unroll
                for (int ni = 0; ni < 4; ++ni)
                    ac[mi][ni] = __builtin_amdgcn_mfma_f32_16x16x32_bf16(a[mi], b[ni], ac[mi][ni], 0, 0, 0);
        }
    };

    stage(0, 0);
    __syncthreads();                             // buffer0 staged; wcS/scS/sfS visible
    if constexpr (EPI == 3) {
        rmwBN(0, 0);
        __syncthreads();
    }
    for (int s = 0; s < 4; ++s) {
        if (s + 1 < 4) stage(s + 1, (s + 1) & 1);
        compute_step(Bp, s, acc);
        __syncthreads();
        if (EPI == 3 && s + 1 == 1) {            // buffer1 = Y1 half 2
            rmwBN(1, 1);
            __syncthreads();
        }
    }

    float bv[4];
#pragma unroll
    for (int ni = 0; ni < 4; ++ni) bv[ni] = bias[c0 + ni * 16 + m];

    if constexpr (EPI == 1 || EPI == 3) {
        // ---- write Y (bias+act, bf16) into the full tile in staged layout ----
        const int bufo = (wave & 1) * 8192;
#pragma unroll
        for (int mi = 0; mi < 4; ++mi)
#pragma unroll
            for (int ni = 0; ni < 4; ++ni) {
                const int chunk = ni * 2 + (m >> 3);
#pragma unroll
                for (int rg = 0; rg < 4; ++rg) {
                    const int r = rw + mi * 16 + q * 4 + rg;
                    float v = acc[mi][ni][rg] + bv[ni];
                    if (act == 1) v = v > 0.f ? v : 0.f;
                    else if (act == 2) v = v > 0.f ? v : v * NEG_SLOPE;
                    tile[bufo + r * 64 + ((chunk ^ (r & 7)) << 3) + (m & 7)] = (short)f2bf(v);
                }
            }
        __syncthreads();
    }

    if constexpr (EPI == 1) {
        // ---- store Y from tile ----
        {
            const int r = tid >> 1, half = tid & 1;
            const int grow = r0 + r;
            if (grow < n_rows) {
#pragma unroll
                for (int c = 0; c < 8; ++c) {
                    bf16x8 vv = *(const bf16x8*)&tile[half * 8192 + r * 64 + ((c ^ (r & 7)) << 3)];
                    *(bf16x8*)(Cout + (size_t)grow * F + half * 64 + c * 8) = vv;
                }
            }
        }
        // ---- hp = relu(Ytile @ Bp2 + bias2), identical schedule to gemm4 ----
        f32x4 ac2[4][4];
#pragma unroll
        for (int i = 0; i < 4; ++i)
#pragma unroll
            for (int j = 0; j < 4; ++j)
#pragma unroll
                for (int r = 0; r < 4; ++r) ac2[i][j][r] = 0.f;
        compute_step(Bp2, 0, ac2);
        compute_step(Bp2, 1, ac2);
        __syncthreads();   // all tile reads done -> safe to alias ep

        float bv2[4];
#pragma unroll
        for (int ni = 0; ni < 4; ++ni) bv2[ni] = bias2[c0 + ni * 16 + m];
        short* ep = &tile[wave * 1280];
        const int colc_lo = m >> 3, cin = m & 7;
#pragma unroll
        for (int mi = 0; mi < 4; ++mi) {
#pragma unroll
            for (int ni = 0; ni < 4; ++ni) {
                const int colc = 2 * ni + colc_lo;
#pragma unroll
                for (int rg = 0; rg < 4; ++rg) {
                    const int row16 = q * 4 + rg;
                    float v = ac2[mi][ni][rg] + bv2[ni];
                    v = v > 0.f ? v : 0.f;
                    ep[row16 * 80 + ((colc ^ (row16 & 7)) << 3) + cin] = (short)f2bf(v);
                }
            }
            __syncthreads();
#pragma unroll
            for (int p = 0; p < 2; ++p) {
                const int lrow = (lane >> 3) + 8 * p;
                bf16x8 vv = *(const bf16x8*)&ep[lrow * 80 + (((lane & 7) ^ (lrow & 7)) << 3)];
                const int grow = r0q + mi * 16 + lrow;
                if (grow < n_rows)
                    *(bf16x8*)(Cout2 + (size_t)grow * F + c0 + ((lane & 7) << 3)) = vv;
            }
            __syncthreads();
        }
    }

    if constexpr (EPI == 2) {
        // ---- BN stats partials from rounded values (+ standard Y epilogue) ----
        float* shf = (float*)&tile[8192];        // buffer1 area; ep uses buffer0 only
        {
            float s4[4] = {0.f, 0.f, 0.f, 0.f}, ss4[4] = {0.f, 0.f, 0.f, 0.f};
#pragma unroll
            for (int mi = 0; mi < 4; ++mi)
#pragma unroll
                for (int rg = 0; rg < 4; ++rg) {
                    const int grow = r0q + mi * 16 + q * 4 + rg;
                    const bool valid = grow < n_rows;
#pragma unroll
                    for (int ni = 0; ni < 4; ++ni) {
                        float v = bf2f(f2bf(acc[mi][ni][rg] + bv[ni]));  // act=0 layer
                        if (valid) { s4[ni] += v; ss4[ni] = fmaf(v, v, ss4[ni]); }
                    }
                }
#pragma unroll
            for (int ni = 0; ni < 4; ++ni) {
                s4[ni]  += __shfl_xor(s4[ni], 16);  s4[ni]  += __shfl_xor(s4[ni], 32);
                ss4[ni] += __shfl_xor(ss4[ni], 16); ss4[ni] += __shfl_xor(ss4[ni], 32);
            }
            if (lane < 16) {
#pragma unroll
                for (int ni = 0; ni < 4; ++ni) {
                    shf[wave * 128 + m * 8 + ni * 2]     = s4[ni];
                    shf[wave * 128 + m * 8 + ni * 2 + 1] = ss4[ni];
                }
            }
        }
        // standard Y epilogue (buffer0 ep); its first sync covers shf writes
        short* ep = &tile[wave * 1280];
        const int colc_lo = m >> 3, cin = m & 7;
#pragma unroll
        for (int mi = 0; mi < 4; ++mi) {
#pragma unroll
            for (int ni = 0; ni < 4; ++ni) {
                const int colc = 2 * ni + colc_lo;
#pragma unroll
                for (int rg = 0; rg < 4; ++rg) {
                    const int row16 = q * 4 + rg;
                    float v = acc[mi][ni][rg] + bv[ni];
                    if (act == 1) v = v > 0.f ? v : 0.f;
                    else if (act == 2) v = v > 0.f ? v : v * NEG_SLOPE;
                    ep[row16 * 80 + ((colc ^ (row16 & 7)) << 3) + cin] = (short)f2bf(v);
                }
            }
            __syncthreads();
#pragma unroll
            for (int p = 0; p < 2; ++p) {
                const int lrow = (lane >> 3) + 8 * p;
                bf16x8 vv = *(const bf16x8*)&ep[lrow * 80 + (((lane & 7) ^ (lrow & 7)) << 3)];
                const int grow = r0q + mi * 16 + lrow;
                if (grow < n_rows)
                    *(bf16x8*)(Cout + (size_t)grow * F + c0 + ((lane & 7) << 3)) = vv;
            }
            __syncthreads();
        }
        // combine wave pairs (0+2 cols 0-63, 1+3 cols 64-127), 256 atomics/block
        {
            const int wp = tid >> 7, m2 = (tid >> 3) & 15, j = tid & 7;
            const float val = shf[wp * 128 + m2 * 8 + j] + shf[(wp + 2) * 128 + m2 * 8 + j];
            const int col = wp * 64 + (j >> 1) * 16 + m2;
            atomicAdd(&stats[(j & 1) * 128 + col], val);
        }
    }

    if constexpr (EPI == 3) {
        // ---- classifier: out = Ytile @ Wc + bc (identical k-order fmaf chain) ----
        const int r = tid >> 1, cg = tid & 1;
        float sacc[8];
#pragma unroll
        for (int j = 0; j < 8; ++j) sacc[j] = wcS[2048 + cg * 8 + j];
#pragma unroll
        for (int k8 = 0; k8 < 16; ++k8) {
            const int buf = k8 >> 3, ch = k8 & 7;
            bf16x8 xa = *(const bf16x8*)&tile[buf * 8192 + r * 64 + ((ch ^ (r & 7)) << 3)];
#pragma unroll
            for (int e = 0; e < 8; ++e) {
                const float xv = bf2f((unsigned short)xa[e]);
                const float* wr = &wcS[(k8 * 8 + e) * 16 + cg * 8];
#pragma unroll
                for (int j = 0; j < 8; ++j) sacc[j] = fmaf(xv, wr[j], sacc[j]);
            }
        }
        const int grow = r0 + r;
        if (grow < n_rows) {
            float4 o0 = make_float4(sacc[0], sacc[1], sacc[2], sacc[3]);
            float4 o1 = make_float4(sacc[4], sacc[5], sacc[6], sacc[7]);
            *(float4*)(out + (size_t)grow * 16 + cg * 8) = o0;
            *(float4*)(out + (size_t)grow * 16 + cg * 8 + 4) = o1;
        }
    }
}

// ---------------- CSR scan (row_start only) ----------------
__global__ __launch_bounds__(256) void scan1_kernel(const int* __restrict__ deg, int* __restrict__ bsum) {
    __shared__ int sh[256];
    const int t = threadIdx.x;
    const int base = blockIdx.x * 1024 + t * 4;
    int s = 0;
#pragma unroll
    for (int j = 0; j < 4; ++j) s += (base + j < N_NODES) ? deg[base + j] : 0;
    sh[t] = s; __syncthreads();
    for (int off = 128; off; off >>= 1) {
        if (t < off) sh[t] += sh[t + off];
        __syncthreads();
    }
    if (t == 0) bsum[blockIdx.x] = sh[0];
}

__global__ __launch_bounds__(128) void scan2_kernel(int* __restrict__ bsum, int nb, int* __restrict__ row_start) {
    __shared__ int sh[128];
    const int t = threadIdx.x;
    sh[t] = (t < nb) ? bsum[t] : 0;
    __syncthreads();
    for (int off = 1; off < 128; off <<= 1) {
        int x = (t >= off) ? sh[t - off] : 0;
        __syncthreads();
        if (t >= off) sh[t] += x;
        __syncthreads();
    }
    if (t < nb) bsum[t] = t ? sh[t - 1] : 0;
    if (t == 0) row_start[N_NODES] = N_EDGES;
}

__global__ __launch_bounds__(256) void scan3_kernel(
    const int* __restrict__ deg, const int* __restrict__ boff,
    int* __restrict__ row_start)
{
    __shared__ int sh[256];
    const int t = threadIdx.x;
    const int base = blockIdx.x * 1024 + t * 4;
    int v[4]; int s = 0;
#pragma unroll
    for (int j = 0; j < 4; ++j) { v[j] = (base + j < N_NODES) ? deg[base + j] : 0; s += v[j]; }
    sh[t] = s; __syncthreads();
    for (int off = 1; off < 256; off <<= 1) {
        int x = (t >= off) ? sh[t - off] : 0;
        __syncthreads();
        if (t >= off) sh[t] += x;
        __syncthreads();
    }
    int excl = (t ? sh[t - 1] : 0) + boff[blockIdx.x];
#pragma unroll
    for (int j = 0; j < 4; ++j) {
        if (base + j < N_NODES) row_start[base + j] = excl;
        excl += v[j];
    }
}

// ---------------- fused scatter (atomic-free, rank-based) | layer-0 fc_pool GEMM ----
__global__ __launch_bounds__(256) void scatter_gemm_kernel(
    const int* __restrict__ src, const int* __restrict__ dst,
    const unsigned short* __restrict__ erank, const int* __restrict__ row_start,
    int* __restrict__ esrc,
    const short* __restrict__ A1, const short* __restrict__ Bp,
    const float* __restrict__ bias, unsigned short* __restrict__ Cout)
{
    const int bid = blockIdx.x;
    const int sgrp = bid / 13;
    const int u = bid - sgrp * 13;
    if (u < 5) {
        const int sid = sgrp * 5 + u;                // 0..489
        const int e0 = sid * 2048 + threadIdx.x;
        if (e0 >= N_EDGES) return;
        int d[8], sv[8]; int rk[8]; bool ok[8];
#pragma unroll
        for (int j = 0; j < 8; ++j) {
            const int e = e0 + j * 256;
            const int ec = min(e, N_EDGES - 1);
            ok[j] = e < N_EDGES;
            d[j] = dst[ec];
            sv[j] = src[ec];
            rk[j] = erank[ec];
        }
        int pos[8];
#pragma unroll
        for (int j = 0; j < 8; ++j) pos[j] = row_start[d[j]] + rk[j];
#pragma unroll
        for (int j = 0; j < 8; ++j)
            if (ok[j]) esrc[pos[j]] = sv[j];
    } else {
        // ---- layer-0 fc_pool GEMM (independent of CSR) ----
        const int g = sgrp * 8 + (u - 5);
        if (g >= (N_NODES + 127) / 128) return;
        gemm_body<4, false>(g, A1, (const short*)nullptr, Bp, bias, Cout,
                            N_NODES, 1, nullptr, nullptr, nullptr);
    }
}

// ---------------- aggregation: wave per node, clamped single-round gather, pk_max ----
__global__ __launch_bounds__(256) void aggregate_max_bf16(
    const unsigned int* __restrict__ hp, const int* __restrict__ row_start,
    const int* __restrict__ esrc, unsigned int* __restrict__ agg)
{
    const int node = blockIdx.x * 4 + (threadIdx.x >> 6);
    if (node >= N_NODES) return;
    const int lane = threadIdx.x & 63;
    const int beg = row_start[node], end = row_start[node + 1];
    u16x2 mm = (u16x2)0;
    for (int base = beg; base < end; base += 16) {
        int s[16];
#pragma unroll
        for (int j = 0; j < 16; ++j) {
            const int t = base + j;
            s[j] = esrc[(t < end) ? t : beg];
        }
        unsigned int v[16];
#pragma unroll
        for (int j = 0; j < 16; ++j) v[j] = hp[(size_t)s[j] * 64 + lane];
#pragma unroll
        for (int j = 0; j < 16; ++j)
            mm = __builtin_elementwise_max(mm, __builtin_bit_cast(u16x2, v[j]));   // v_pk_max_u16
    }
    agg[(size_t)node * 64 + lane] = __builtin_bit_cast(unsigned int, mm);
}

extern "C" void kernel_launch(void* const* d_in, const int* in_sizes, int n_in,
                              void* d_out, int out_size, void* d_ws, size_t ws_size,
                              hipStream_t stream) {
    const float* node_feat = (const float*)d_in[0];
    const int* src = (const int*)d_in[1];
    const int* dst = (const int*)d_in[2];
    const float* wp[3] = {(const float*)d_in[3],  (const float*)d_in[8],  (const float*)d_in[13]};
    const float* bp[3] = {(const float*)d_in[4],  (const float*)d_in[9],  (const float*)d_in[14]};
    const float* wsm[3] = {(const float*)d_in[5], (const float*)d_in[10], (const float*)d_in[15]};
    const float* wn[3] = {(const float*)d_in[6],  (const float*)d_in[11], (const float*)d_in[16]};
    const float* bb[3] = {(const float*)d_in[7],  (const float*)d_in[12], (const float*)d_in[17]};
    const float* gamma = (const float*)d_in[18];
    const float* beta  = (const float*)d_in[19];
    const float* wc    = (const float*)d_in[20];
    const float* bc    = (const float*)d_in[21];

    const size_t SZ = (size_t)N_NODES * F;          // 12.8M elements
    short* sbase = (short*)d_ws;
    short* B0  = sbase;
    short* B1  = sbase + SZ;
    short* B2  = sbase + 2 * SZ;
    short* Xbf = sbase + 3 * SZ;
    short* wp_p  = sbase + 4 * SZ;                  // 3 × 16384
    short* wsn_p = wp_p + 3 * 16384;                // 3 × 32768
    float* fbase = (float*)(wsn_p + 3 * 32768);     // 16B-aligned
    float* stats = fbase;                           // 256
    int* ibase = (int*)(fbase + 512);
    int* deg       = ibase;                         // 100000
    int* row_start = ibase + 100000;                // 100001
    int* esrc      = ibase + 300104;                // 1000000
    int* bsum      = ibase + 1300104;               // 128
    unsigned short* erank = (unsigned short*)(ibase + 1300232);   // 1000000 u16

    const int gGemm = (N_NODES + 127) / 128;        // 782
    const int gScan = (N_NODES + 1023) / 1024;      // 98
    const int gAgg  = (N_NODES + 3) / 4;            // 25000

    // ---- zero deg + BN stats ----
    zero_misc_kernel<<<99, 256, 0, stream>>>((float4*)deg, (float4*)stats);

    // ---- convert | hist(+rank) | pack (independent, co-resident) ----
    prep_kernel<<<PREP_GROUPS * 4, 256, 0, stream>>>(
        (const float4*)node_feat, (uint2*)Xbf, dst, deg, erank,
        wp[0], wsm[0], wn[0], wp[1], wsm[1], wn[1], wp[2], wsm[2], wn[2],
        wp_p, wsn_p);

    // ---- CSR scan chain (row_start only) ----
    scan1_kernel<<<gScan, 256, 0, stream>>>(deg, bsum);
    scan2_kernel<<<1, 128, 0, stream>>>(bsum, gScan, row_start);
    scan3_kernel<<<gScan, 256, 0, stream>>>(deg, bsum, row_start);

    // ---- scatter (rank-based, no atomics) | layer-0 fc_pool GEMM: hp_0 -> B0 ----
    scatter_gemm_kernel<<<98 * 13, 256, 0, stream>>>(
        src, dst, erank, row_start, esrc,
        Xbf, wp_p, bp[0], (unsigned short*)B0);

    // ---- layer 0: agg_0 -> B1; Y_0 -> B1 (in-place over agg), hp_1 -> B0 ----
    aggregate_max_bf16<<<gAgg, 256, 0, stream>>>(
        (const unsigned int*)B0, row_start, esrc, (unsigned int*)B1);
    gemm8_fused<1><<<gGemm, 256, 0, stream>>>(
        Xbf, B1, wsn_p, bb[0], (unsigned short*)B1,
        wp_p + 16384, bp[1], (unsigned short*)B0,
        nullptr, nullptr, nullptr, nullptr, nullptr, nullptr, N_NODES, 2);

    // ---- layer 1: agg_1 -> B2; Y_1 (RAW, act=0) -> B2 (in-place) + BN stats ----
    aggregate_max_bf16<<<gAgg, 256, 0, stream>>>(
        (const unsigned int*)B0, row_start, esrc, (unsigned int*)B2);
    gemm8_fused<2><<<gGemm, 256, 0, stream>>>(
        B1, B2, wsn_p + 32768, bb[1], (unsigned short*)B2,
        nullptr, nullptr, nullptr,
        stats, nullptr, nullptr, nullptr, nullptr, nullptr, N_NODES, 0);

    // ---- layer 2 (BN via in-LDS RMW in consumers; bn_apply/bn_finalize deleted):
    //      hp_2 = relu(bnleaky(Y1)@Wp2+bp2) -> B0; agg_2 -> B1;
    //      Y_2 from bnleaky(Y1)@Ws + agg@Wn -> classifier -> out ----
    gemm_mfma4_bn<<<gGemm, 256, 0, stream>>>(B2,
        wp_p + 2 * 16384, bp[2], (unsigned short*)B0, N_NODES, 1,
        stats, gamma, beta);
    aggregate_max_bf16<<<gAgg, 256, 0, stream>>>(
        (const unsigned int*)B0, row_start, esrc, (unsigned int*)B1);
    gemm8_fused<3><<<gGemm, 256, 0, stream>>>(
        B2, B1, wsn_p + 2 * 32768, bb[2], nullptr,
        nullptr, nullptr, nullptr,
        stats, wc, bc, (float*)d_out, gamma, beta, N_NODES, 0);
}

// Round 12
// 509.124 us; speedup vs baseline: 1.0112x; 1.0112x over previous
//
#include <hip/hip_runtime.h>

// GraphSAGE-pool ×3 + BN + classifier, bf16 activations + MFMA GEMMs.
// R25 = R24 with the BN region CONFINED TO A PROLOGUE:
//  R24's two rmwBN sites (pre-loop + mid-loop) let the compiler hoist the
//  32 sc/sf LDS loads across the whole unrolled K-loop -> VGPR stayed 160,
//  occ 8.3%. Now both Y1 halves are pre-staged (bufs 0+1, 32KB in flight),
//  ONE barrier, both buffers RMW'd in one contiguous region (coeffs die
//  before any MFMA), barrier, then the K-loop with agg staged mid-loop
//  (stage(2) overlaps compute(1), stage(3) overlaps compute(2)).
//  gemm_mfma4_bn: prestage both -> RMW both -> compute x2.
//  EPI1/EPI2 + non-BN gemm4 keep the R17 schedule exactly.
//  LDS bits after RMW bit-identical to R24 -> output unchanged.

#define N_NODES 100000
#define N_EDGES 1000000
#define F 128
#define NEG_SLOPE 0.01f
#define BN_EPS 1e-5f

typedef __attribute__((ext_vector_type(8))) short bf16x8;
typedef __attribute__((ext_vector_type(4))) float f32x4;
typedef __attribute__((ext_vector_type(2))) unsigned short u16x2;

typedef __attribute__((address_space(3))) unsigned int as3_uint;
typedef __attribute__((address_space(1))) const unsigned int as1_cuint;

__device__ __forceinline__ void gload16(const void* g, void* l) {
    __builtin_amdgcn_global_load_lds((as1_cuint*)g, (as3_uint*)l, 16, 0, 0);
}

__device__ __forceinline__ unsigned short f2bf(float f) {
    unsigned int u = __float_as_uint(f);
    u += 0x7fff + ((u >> 16) & 1);          // RNE
    return (unsigned short)(u >> 16);
}
__device__ __forceinline__ float bf2f(unsigned short h) {
    return __uint_as_float(((unsigned int)h) << 16);
}

// ---------------- combined zero fill: deg (25000 f4) + stats (64 f4) ----------------
__global__ __launch_bounds__(256) void zero_misc_kernel(
    float4* __restrict__ deg4, float4* __restrict__ stats4)
{
    if (blockIdx.x < 98) {
        const int i = blockIdx.x * 256 + threadIdx.x;
        if (i < 25000) deg4[i] = make_float4(0.f, 0.f, 0.f, 0.f);
    } else {
        if (threadIdx.x < 64) stats4[threadIdx.x] = make_float4(0.f, 0.f, 0.f, 0.f);
    }
}

// ---------------- fused prep: f32->bf16 convert | degree hist(+rank) | weight pack ----
#define PREP_GROUPS 4483
__global__ __launch_bounds__(256) void prep_kernel(
    const float4* __restrict__ nf, uint2* __restrict__ xout,
    const int* __restrict__ dst, int* __restrict__ deg,
    unsigned short* __restrict__ erank,
    const float* __restrict__ w0, const float* __restrict__ w1, const float* __restrict__ w2,
    const float* __restrict__ w3, const float* __restrict__ w4, const float* __restrict__ w5,
    const float* __restrict__ w6, const float* __restrict__ w7, const float* __restrict__ w8,
    short* __restrict__ wp_p, short* __restrict__ wsn_p)
{
    const int g = blockIdx.x >> 2;
    const int k = blockIdx.x & 3;
    const int tid = threadIdx.x;
    if (k < 3) {
        // ---- fp32 -> bf16 convert ----
        const int c = g * 3 + k;
        if (c >= 12500) return;
        const long i = (long)c * 256 + tid;
        float4 v = nf[i];
        uint2 o;
        o.x = (unsigned)f2bf(v.x) | ((unsigned)f2bf(v.y) << 16);
        o.y = (unsigned)f2bf(v.z) | ((unsigned)f2bf(v.w) << 16);
        xout[i] = o;
        return;
    }
    if (g < 3907) {
        // ---- degree histogram; keep the return = edge's rank within dst node ----
        const int e = g * 256 + tid;
        if (e < N_EDGES) {
            const int d = __builtin_nontemporal_load(&dst[e]);
            erank[e] = (unsigned short)atomicAdd(&deg[d], 1);
        }
        return;
    }
    const int po = g - 3907;
    if (po >= 576) return;
    // ---- weight pack: f32 [128][128] -> bf16 frag-order [16][128][8] ----
    const int idx = po * 256 + tid;                 // 0 .. 147455
    const int matid = idx >> 14;                    // 0..8, block-uniform
    const int layer = (matid * 11) >> 5;            // /3
    const int mat = matid - 3 * layer;
    const int i = idx & 16383;
    const int kk = i >> 7, n = i & 127;
    const float* srcm;
    switch (matid) {
        case 0: srcm = w0; break; case 1: srcm = w1; break; case 2: srcm = w2; break;
        case 3: srcm = w3; break; case 4: srcm = w4; break; case 5: srcm = w5; break;
        case 6: srcm = w6; break; case 7: srcm = w7; break; default: srcm = w8; break;
    }
    const int slot = ((kk >> 3) * 128 + n) * 8 + (kk & 7);
    const short v = (short)f2bf(srcm[i]);
    if (mat == 0) wp_p[layer * 16384 + slot] = v;
    else wsn_p[layer * 32768 + (mat == 2 ? 16384 : 0) + slot] = v;
}

// ---------------- MFMA GEMM body, m97-style (R17); BN via prologue-confined RMW ----
template<int NKS, bool BN>
__device__ __forceinline__ void gemm_body(
    const int bid,
    const short* __restrict__ A1, const short* __restrict__ A2,
    const short* __restrict__ Bp, const float* __restrict__ bias,
    unsigned short* __restrict__ Cout, const int n_rows, const int act,
    const float* __restrict__ stats, const float* __restrict__ gamma,
    const float* __restrict__ beta)
{
    constexpr int S = NKS / 2;                   // BK=64 steps
    __shared__ short tile[2 * 8192];             // 2 x (128 rows x 64 cols); reused as epilogue bounce
    __shared__ float scS[BN ? 128 : 1];
    __shared__ float sfS[BN ? 128 : 1];

    const int tid = threadIdx.x;
    const int wave = tid >> 6;
    const int lane = tid & 63;
    const int m = lane & 15, q = lane >> 4;
    const int r0 = bid * 128;
    const int rw = (wave >> 1) * 64;             // wave row-quadrant offset
    const int r0q = r0 + rw;
    const int c0 = (wave & 1) * 64;
    const int gchunk = (tid & 7) ^ ((tid >> 3) & 7);

    if constexpr (BN) {
        if (tid < 128) {
            const float inv = 1.f / N_NODES;
            const float mean = stats[tid] * inv;
            const float var = stats[128 + tid] * inv - mean * mean;
            const float sc = gamma[tid] * rsqrtf(var + BN_EPS);
            scS[tid] = sc;
            sfS[tid] = fmaf(-mean, sc, beta[tid]);
        }
    }

    f32x4 acc[4][4];
#pragma unroll
    for (int i = 0; i < 4; ++i)
#pragma unroll
        for (int j = 0; j < 4; ++j)
#pragma unroll
            for (int r = 0; r < 4; ++r) acc[i][j][r] = 0.f;

    auto stage = [&](int s, int buf) {
        const short* Ap = (NKS == 8 && s >= 2) ? A2 : A1;
        const int kbase = (s & 1) * 64;          // shorts
#pragma unroll
        for (int p = 0; p < 4; ++p) {
            int row = r0 + (tid >> 3) + 32 * p;
            row = min(row, n_rows - 1);
            gload16(Ap + (size_t)row * F + kbase + gchunk * 8,
                    &tile[buf * 8192 + p * 2048 + tid * 8]);
        }
    };

    // in-LDS BN transform of this thread's own staged slots (prologue only)
    auto rmwBN = [&](int s, int buf) {
        const int kbase = (s & 1) * 64;
        float scv[8], sfv[8];
#pragma unroll
        for (int e = 0; e < 8; ++e) {
            scv[e] = scS[kbase + gchunk * 8 + e];
            sfv[e] = sfS[kbase + gchunk * 8 + e];
        }
#pragma unroll
        for (int p = 0; p < 4; ++p) {
            unsigned int* slot = (unsigned int*)&tile[buf * 8192 + p * 2048 + tid * 8];
            const unsigned int w[4] = {slot[0], slot[1], slot[2], slot[3]};
#pragma unroll
            for (int j = 0; j < 4; ++j) {
                float lo = fmaf(bf2f((unsigned short)(w[j] & 0xffffu)), scv[2 * j], sfv[2 * j]);
                float hi = fmaf(bf2f((unsigned short)(w[j] >> 16)), scv[2 * j + 1], sfv[2 * j + 1]);
                lo = lo > 0.f ? lo : lo * NEG_SLOPE;
                hi = hi > 0.f ? hi : hi * NEG_SLOPE;
                slot[j] = (unsigned)f2bf(lo) | ((unsigned)f2bf(hi) << 16);
            }
        }
    };

    auto compute_step = [&](int s) {
        const short* tb = &tile[(s & 1) * 8192];
#pragma unroll
        for (int ks2 = 0; ks2 < 2; ++ks2) {
            const int ks32 = s * 2 + ks2;
            bf16x8 b[4], a[4];
#pragma unroll
            for (int ni = 0; ni < 4; ++ni)
                b[ni] = *(const bf16x8*)(Bp + ((size_t)(ks32 * 4 + q) * F + c0 + ni * 16 + m) * 8);
#pragma unroll
            for (int mi = 0; mi < 4; ++mi)
                a[mi] = *(const bf16x8*)(tb + (rw + mi * 16 + m) * 64 + (((ks2 * 4 + q) ^ (m & 7)) << 3));
#pragma unroll
            for (int mi = 0; mi < 4; ++mi)
#pragma unroll
                for (int ni = 0; ni < 4; ++ni)
                    acc[mi][ni] = __builtin_amdgcn_mfma_f32_16x16x32_bf16(a[mi], b[ni], acc[mi][ni], 0, 0, 0);
        }
    };

    if constexpr (BN) {
        // prologue: both Y1 halves staged + RMW'd in one region; coeffs die here
        stage(0, 0); stage(1, 1);
        __syncthreads();                         // both staged; scS/sfS visible
        rmwBN(0, 0); rmwBN(1, 1);
        __syncthreads();
        compute_step(0);
        compute_step(1);
        __syncthreads();                         // tile reads done -> epilogue alias
    } else {
        stage(0, 0);
        __syncthreads();
        for (int s = 0; s < S; ++s) {
            if (s + 1 < S) stage(s + 1, (s + 1) & 1);
            compute_step(s);
            __syncthreads();
        }
    }

    float bv[4];
#pragma unroll
    for (int ni = 0; ni < 4; ++ni) bv[ni] = bias[c0 + ni * 16 + m];

    short* ep = &tile[wave * 1280];              // aliased onto dead A-tile buffer
    const int colc_lo = m >> 3, cin = m & 7;
#pragma unroll
    for (int mi = 0; mi < 4; ++mi) {
#pragma unroll
        for (int ni = 0; ni < 4; ++ni) {
            const int colc = 2 * ni + colc_lo;
#pragma unroll
            for (int rg = 0; rg < 4; ++rg) {
                const int row16 = q * 4 + rg;
                float v = acc[mi][ni][rg] + bv[ni];
                if (act == 1) v = v > 0.f ? v : 0.f;
                else if (act == 2) v = v > 0.f ? v : v * NEG_SLOPE;
                ep[row16 * 80 + ((colc ^ (row16 & 7)) << 3) + cin] = (short)f2bf(v);
            }
        }
        __syncthreads();
#pragma unroll
        for (int p = 0; p < 2; ++p) {
            const int lrow = (lane >> 3) + 8 * p;
            bf16x8 vv = *(const bf16x8*)&ep[lrow * 80 + (((lane & 7) ^ (lrow & 7)) << 3)];
            const int grow = r0q + mi * 16 + lrow;
            if (grow < n_rows)
                *(bf16x8*)(Cout + (size_t)grow * F + c0 + ((lane & 7) << 3)) = vv;
        }
        __syncthreads();
    }
}

// layer-2 fc_pool: hp2 = relu( bnleaky(Y1) @ Wp2 + bp2 ), BN prologue RMW
__global__ __launch_bounds__(256) void gemm_mfma4_bn(
    const short* __restrict__ A1,
    const short* __restrict__ Bp, const float* __restrict__ bias,
    unsigned short* __restrict__ Cout, int n_rows, int act,
    const float* __restrict__ stats, const float* __restrict__ gamma,
    const float* __restrict__ beta)
{
    gemm_body<4, true>(blockIdx.x, A1, (const short*)nullptr, Bp, bias, Cout,
                       n_rows, act, stats, gamma, beta);
}

// ---------------- fused NKS=8 Y-GEMM (R17) with per-layer tail (EPI) ----------------
// EPI=1: +hp-GEMM (Y@Bp2+bias2, relu) -> Cout2;  Y stored to Cout.
// EPI=2: +BN stats partial accumulation into stats[]; Y stored to Cout.
// EPI=3: +classifier (Ytile@Wc+bc) -> out; Y NOT stored; BN prologue RMW on A1 halves.
template<int EPI>
__global__ __launch_bounds__(256) void gemm8_fused(
    const short* __restrict__ A1, const short* __restrict__ A2,
    const short* __restrict__ Bp, const float* __restrict__ bias,
    unsigned short* __restrict__ Cout,
    const short* __restrict__ Bp2, const float* __restrict__ bias2,
    unsigned short* __restrict__ Cout2,
    float* __restrict__ stats,
    const float* __restrict__ Wc, const float* __restrict__ bc,
    float* __restrict__ out,
    const float* __restrict__ gamma, const float* __restrict__ beta,
    int n_rows, int act)
{
    __shared__ short tile[2 * 8192];
    __shared__ float wcS[EPI == 3 ? 2064 : 4];   // 2048 Wc + 16 bc (EPI3 only)
    __shared__ float scS[EPI == 3 ? 128 : 1];
    __shared__ float sfS[EPI == 3 ? 128 : 1];

    const int tid = threadIdx.x;
    const int wave = tid >> 6;
    const int lane = tid & 63;
    const int m = lane & 15, q = lane >> 4;
    const int r0 = blockIdx.x * 128;
    const int rw = (wave >> 1) * 64;
    const int r0q = r0 + rw;
    const int c0 = (wave & 1) * 64;
    const int gchunk = (tid & 7) ^ ((tid >> 3) & 7);

    if constexpr (EPI == 3) {
        for (int i = tid; i < 2048; i += 256) wcS[i] = Wc[i];
        if (tid < 16) wcS[2048 + tid] = bc[tid];
        if (tid < 128) {
            const float inv = 1.f / N_NODES;
            const float mean = stats[tid] * inv;
            const float var = stats[128 + tid] * inv - mean * mean;
            const float sc = gamma[tid] * rsqrtf(var + BN_EPS);
            scS[tid] = sc;
            sfS[tid] = fmaf(-mean, sc, beta[tid]);
        }
    }

    f32x4 acc[4][4];
#pragma unroll
    for (int i = 0; i < 4; ++i)
#pragma unroll
        for (int j = 0; j < 4; ++j)
#pragma unroll
            for (int r = 0; r < 4; ++r) acc[i][j][r] = 0.f;

    auto stage = [&](int s, int buf) {
        const short* Ap = (s >= 2) ? A2 : A1;
        const int kbase = (s & 1) * 64;
#pragma unroll
        for (int p = 0; p < 4; ++p) {
            int row = r0 + (tid >> 3) + 32 * p;
            row = min(row, n_rows - 1);
            gload16(Ap + (size_t)row * F + kbase + gchunk * 8,
                    &tile[buf * 8192 + p * 2048 + tid * 8]);
        }
    };

    auto rmwBN = [&](int s, int buf) {
        const int kbase = (s & 1) * 64;
        float scv[8], sfv[8];
#pragma unroll
        for (int e = 0; e < 8; ++e) {
            scv[e] = scS[kbase + gchunk * 8 + e];
            sfv[e] = sfS[kbase + gchunk * 8 + e];
        }
#pragma unroll
        for (int p = 0; p < 4; ++p) {
            unsigned int* slot = (unsigned int*)&tile[buf * 8192 + p * 2048 + tid * 8];
            const unsigned int w[4] = {slot[0], slot[1], slot[2], slot[3]};
#pragma unroll
            for (int j = 0; j < 4; ++j) {
                float lo = fmaf(bf2f((unsigned short)(w[j] & 0xffffu)), scv[2 * j], sfv[2 * j]);
                float hi = fmaf(bf2f((unsigned short)(w[j] >> 16)), scv[2 * j + 1], sfv[2 * j + 1]);
                lo = lo > 0.f ? lo : lo * NEG_SLOPE;
                hi = hi > 0.f ? hi : hi * NEG_SLOPE;
                slot[j] = (unsigned)f2bf(lo) | ((unsigned)f2bf(hi) << 16);
            }
        }
    };

    auto compute_step = [&](const short* __restrict__ Bpp, int s, f32x4 (&ac)[4][4]) {
        const short* tb = &tile[(s & 1) * 8192];
#pragma unroll
        for (int ks2 = 0; ks2 < 2; ++ks2) {
            const int ks32 = s * 2 + ks2;
            bf16x8 b[4], a[4];
#pragma unroll
            for (int ni = 0; ni < 4; ++ni)
                b[ni] = *(const bf16x8*)(Bpp + ((size_t)(ks32 * 4 + q) * F + c0 + ni * 16 + m) * 8);
#pragma unroll
            for (int mi = 0; mi < 4; ++mi)
                a[mi] = *(const bf16x8*)(tb + (rw + mi * 16 + m) * 64 + (((ks2 * 4 + q) ^ (m & 7)) << 3));
#pragma unroll
            for (int mi = 0; mi < 4; ++mi)
#pragma unroll
                for (int ni = 0; ni < 4; ++ni)
                    ac[mi][ni] = __builtin_amdgcn_mfma_f32_16x16x32_bf16(a[mi], b[ni], ac[mi][ni], 0, 0, 0);
        }
    };

    if constexpr (EPI == 3) {
        // prologue: both Y1 halves staged + RMW'd; coeffs die before K-loop
        stage(0, 0); stage(1, 1);
        __syncthreads();                         // staged; wcS/scS/sfS visible
        rmwBN(0, 0); rmwBN(1, 1);
        __syncthreads();
        compute_step(Bp, 0, acc);
        __syncthreads();
        stage(2, 0);                             // agg half0 -> buf0
        compute_step(Bp, 1, acc);
        __syncthreads();
        stage(3, 1);                             // agg half1 -> buf1
        compute_step(Bp, 2, acc);
        __syncthreads();
        compute_step(Bp, 3, acc);
        __syncthreads();
    } else {
        stage(0, 0);
        __syncthreads();
        for (int s = 0; s < 4; ++s) {
            if (s + 1 < 4) stage(s + 1, (s + 1) & 1);
            compute_step(Bp, s, acc);
            __syncthreads();
        }
    }

    float bv[4];
#pragma unroll
    for (int ni = 0; ni < 4; ++ni) bv[ni] = bias[c0 + ni * 16 + m];

    if constexpr (EPI == 1 || EPI == 3) {
        // ---- write Y (bias+act, bf16) into the full tile in staged layout ----
        const int bufo = (wave & 1) * 8192;
#pragma unroll
        for (int mi = 0; mi < 4; ++mi)
#pragma unroll
            for (int ni = 0; ni < 4; ++ni) {
                const int chunk = ni * 2 + (m >> 3);
#pragma unroll
                for (int rg = 0; rg < 4; ++rg) {
                    const int r = rw + mi * 16 + q * 4 + rg;
                    float v = acc[mi][ni][rg] + bv[ni];
                    if (act == 1) v = v > 0.f ? v : 0.f;
                    else if (act == 2) v = v > 0.f ? v : v * NEG_SLOPE;
                    tile[bufo + r * 64 + ((chunk ^ (r & 7)) << 3) + (m & 7)] = (short)f2bf(v);
                }
            }
        __syncthreads();
    }

    if constexpr (EPI == 1) {
        // ---- store Y from tile ----
        {
            const int r = tid >> 1, half = tid & 1;
            const int grow = r0 + r;
            if (grow < n_rows) {
#pragma unroll
                for (int c = 0; c < 8; ++c) {
                    bf16x8 vv = *(const bf16x8*)&tile[half * 8192 + r * 64 + ((c ^ (r & 7)) << 3)];
                    *(bf16x8*)(Cout + (size_t)grow * F + half * 64 + c * 8) = vv;
                }
            }
        }
        // ---- hp = relu(Ytile @ Bp2 + bias2), identical schedule to gemm4 ----
        f32x4 ac2[4][4];
#pragma unroll
        for (int i = 0; i < 4; ++i)
#pragma unroll
            for (int j = 0; j < 4; ++j)
#pragma unroll
                for (int r = 0; r < 4; ++r) ac2[i][j][r] = 0.f;
        compute_step(Bp2, 0, ac2);
        compute_step(Bp2, 1, ac2);
        __syncthreads();   // all tile reads done -> safe to alias ep

        float bv2[4];
#pragma unroll
        for (int ni = 0; ni < 4; ++ni) bv2[ni] = bias2[c0 + ni * 16 + m];
        short* ep = &tile[wave * 1280];
        const int colc_lo = m >> 3, cin = m & 7;
#pragma unroll
        for (int mi = 0; mi < 4; ++mi) {
#pragma unroll
            for (int ni = 0; ni < 4; ++ni) {
                const int colc = 2 * ni + colc_lo;
#pragma unroll
                for (int rg = 0; rg < 4; ++rg) {
                    const int row16 = q * 4 + rg;
                    float v = ac2[mi][ni][rg] + bv2[ni];
                    v = v > 0.f ? v : 0.f;
                    ep[row16 * 80 + ((colc ^ (row16 & 7)) << 3) + cin] = (short)f2bf(v);
                }
            }
            __syncthreads();
#pragma unroll
            for (int p = 0; p < 2; ++p) {
                const int lrow = (lane >> 3) + 8 * p;
                bf16x8 vv = *(const bf16x8*)&ep[lrow * 80 + (((lane & 7) ^ (lrow & 7)) << 3)];
                const int grow = r0q + mi * 16 + lrow;
                if (grow < n_rows)
                    *(bf16x8*)(Cout2 + (size_t)grow * F + c0 + ((lane & 7) << 3)) = vv;
            }
            __syncthreads();
        }
    }

    if constexpr (EPI == 2) {
        // ---- BN stats partials from rounded values (+ standard Y epilogue) ----
        float* shf = (float*)&tile[8192];        // buffer1 area; ep uses buffer0 only
        {
            float s4[4] = {0.f, 0.f, 0.f, 0.f}, ss4[4] = {0.f, 0.f, 0.f, 0.f};
#pragma unroll
            for (int mi = 0; mi < 4; ++mi)
#pragma unroll
                for (int rg = 0; rg < 4; ++rg) {
                    const int grow = r0q + mi * 16 + q * 4 + rg;
                    const bool valid = grow < n_rows;
#pragma unroll
                    for (int ni = 0; ni < 4; ++ni) {
                        float v = bf2f(f2bf(acc[mi][ni][rg] + bv[ni]));  // act=0 layer
                        if (valid) { s4[ni] += v; ss4[ni] = fmaf(v, v, ss4[ni]); }
                    }
                }
#pragma unroll
            for (int ni = 0; ni < 4; ++ni) {
                s4[ni]  += __shfl_xor(s4[ni], 16);  s4[ni]  += __shfl_xor(s4[ni], 32);
                ss4[ni] += __shfl_xor(ss4[ni], 16); ss4[ni] += __shfl_xor(ss4[ni], 32);
            }
            if (lane < 16) {
#pragma unroll
                for (int ni = 0; ni < 4; ++ni) {
                    shf[wave * 128 + m * 8 + ni * 2]     = s4[ni];
                    shf[wave * 128 + m * 8 + ni * 2 + 1] = ss4[ni];
                }
            }
        }
        // standard Y epilogue (buffer0 ep); its first sync covers shf writes
        short* ep = &tile[wave * 1280];
        const int colc_lo = m >> 3, cin = m & 7;
#pragma unroll
        for (int mi = 0; mi < 4; ++mi) {
#pragma unroll
            for (int ni = 0; ni < 4; ++ni) {
                const int colc = 2 * ni + colc_lo;
#pragma unroll
                for (int rg = 0; rg < 4; ++rg) {
                    const int row16 = q * 4 + rg;
                    float v = acc[mi][ni][rg] + bv[ni];
                    if (act == 1) v = v > 0.f ? v : 0.f;
                    else if (act == 2) v = v > 0.f ? v : v * NEG_SLOPE;
                    ep[row16 * 80 + ((colc ^ (row16 & 7)) << 3) + cin] = (short)f2bf(v);
                }
            }
            __syncthreads();
#pragma unroll
            for (int p = 0; p < 2; ++p) {
                const int lrow = (lane >> 3) + 8 * p;
                bf16x8 vv = *(const bf16x8*)&ep[lrow * 80 + (((lane & 7) ^ (lrow & 7)) << 3)];
                const int grow = r0q + mi * 16 + lrow;
                if (grow < n_rows)
                    *(bf16x8*)(Cout + (size_t)grow * F + c0 + ((lane & 7) << 3)) = vv;
            }
            __syncthreads();
        }
        // combine wave pairs (0+2 cols 0-63, 1+3 cols 64-127), 256 atomics/block
        {
            const int wp = tid >> 7, m2 = (tid >> 3) & 15, j = tid & 7;
            const float val = shf[wp * 128 + m2 * 8 + j] + shf[(wp + 2) * 128 + m2 * 8 + j];
            const int col = wp * 64 + (j >> 1) * 16 + m2;
            atomicAdd(&stats[(j & 1) * 128 + col], val);
        }
    }

    if constexpr (EPI == 3) {
        // ---- classifier: out = Ytile @ Wc + bc (identical k-order fmaf chain) ----
        const int r = tid >> 1, cg = tid & 1;
        float sacc[8];
#pragma unroll
        for (int j = 0; j < 8; ++j) sacc[j] = wcS[2048 + cg * 8 + j];
#pragma unroll
        for (int k8 = 0; k8 < 16; ++k8) {
            const int buf = k8 >> 3, ch = k8 & 7;
            bf16x8 xa = *(const bf16x8*)&tile[buf * 8192 + r * 64 + ((ch ^ (r & 7)) << 3)];
#pragma unroll
            for (int e = 0; e < 8; ++e) {
                const float xv = bf2f((unsigned short)xa[e]);
                const float* wr = &wcS[(k8 * 8 + e) * 16 + cg * 8];
#pragma unroll
                for (int j = 0; j < 8; ++j) sacc[j] = fmaf(xv, wr[j], sacc[j]);
            }
        }
        const int grow = r0 + r;
        if (grow < n_rows) {
            float4 o0 = make_float4(sacc[0], sacc[1], sacc[2], sacc[3]);
            float4 o1 = make_float4(sacc[4], sacc[5], sacc[6], sacc[7]);
            *(float4*)(out + (size_t)grow * 16 + cg * 8) = o0;
            *(float4*)(out + (size_t)grow * 16 + cg * 8 + 4) = o1;
        }
    }
}

// ---------------- CSR scan (row_start only) ----------------
__global__ __launch_bounds__(256) void scan1_kernel(const int* __restrict__ deg, int* __restrict__ bsum) {
    __shared__ int sh[256];
    const int t = threadIdx.x;
    const int base = blockIdx.x * 1024 + t * 4;
    int s = 0;
#pragma unroll
    for (int j = 0; j < 4; ++j) s += (base + j < N_NODES) ? deg[base + j] : 0;
    sh[t] = s; __syncthreads();
    for (int off = 128; off; off >>= 1) {
        if (t < off) sh[t] += sh[t + off];
        __syncthreads();
    }
    if (t == 0) bsum[blockIdx.x] = sh[0];
}

__global__ __launch_bounds__(128) void scan2_kernel(int* __restrict__ bsum, int nb, int* __restrict__ row_start) {
    __shared__ int sh[128];
    const int t = threadIdx.x;
    sh[t] = (t < nb) ? bsum[t] : 0;
    __syncthreads();
    for (int off = 1; off < 128; off <<= 1) {
        int x = (t >= off) ? sh[t - off] : 0;
        __syncthreads();
        if (t >= off) sh[t] += x;
        __syncthreads();
    }
    if (t < nb) bsum[t] = t ? sh[t - 1] : 0;
    if (t == 0) row_start[N_NODES] = N_EDGES;
}

__global__ __launch_bounds__(256) void scan3_kernel(
    const int* __restrict__ deg, const int* __restrict__ boff,
    int* __restrict__ row_start)
{
    __shared__ int sh[256];
    const int t = threadIdx.x;
    const int base = blockIdx.x * 1024 + t * 4;
    int v[4]; int s = 0;
#pragma unroll
    for (int j = 0; j < 4; ++j) { v[j] = (base + j < N_NODES) ? deg[base + j] : 0; s += v[j]; }
    sh[t] = s; __syncthreads();
    for (int off = 1; off < 256; off <<= 1) {
        int x = (t >= off) ? sh[t - off] : 0;
        __syncthreads();
        if (t >= off) sh[t] += x;
        __syncthreads();
    }
    int excl = (t ? sh[t - 1] : 0) + boff[blockIdx.x];
#pragma unroll
    for (int j = 0; j < 4; ++j) {
        if (base + j < N_NODES) row_start[base + j] = excl;
        excl += v[j];
    }
}

// ---------------- fused scatter (atomic-free, rank-based) | layer-0 fc_pool GEMM ----
__global__ __launch_bounds__(256) void scatter_gemm_kernel(
    const int* __restrict__ src, const int* __restrict__ dst,
    const unsigned short* __restrict__ erank, const int* __restrict__ row_start,
    int* __restrict__ esrc,
    const short* __restrict__ A1, const short* __restrict__ Bp,
    const float* __restrict__ bias, unsigned short* __restrict__ Cout)
{
    const int bid = blockIdx.x;
    const int sgrp = bid / 13;
    const int u = bid - sgrp * 13;
    if (u < 5) {
        const int sid = sgrp * 5 + u;                // 0..489
        const int e0 = sid * 2048 + threadIdx.x;
        if (e0 >= N_EDGES) return;
        int d[8], sv[8]; int rk[8]; bool ok[8];
#pragma unroll
        for (int j = 0; j < 8; ++j) {
            const int e = e0 + j * 256;
            const int ec = min(e, N_EDGES - 1);
            ok[j] = e < N_EDGES;
            d[j] = dst[ec];
            sv[j] = src[ec];
            rk[j] = erank[ec];
        }
        int pos[8];
#pragma unroll
        for (int j = 0; j < 8; ++j) pos[j] = row_start[d[j]] + rk[j];
#pragma unroll
        for (int j = 0; j < 8; ++j)
            if (ok[j]) esrc[pos[j]] = sv[j];
    } else {
        // ---- layer-0 fc_pool GEMM (independent of CSR) ----
        const int g = sgrp * 8 + (u - 5);
        if (g >= (N_NODES + 127) / 128) return;
        gemm_body<4, false>(g, A1, (const short*)nullptr, Bp, bias, Cout,
                            N_NODES, 1, nullptr, nullptr, nullptr);
    }
}

// ---------------- aggregation: wave per node, clamped single-round gather, pk_max ----
__global__ __launch_bounds__(256) void aggregate_max_bf16(
    const unsigned int* __restrict__ hp, const int* __restrict__ row_start,
    const int* __restrict__ esrc, unsigned int* __restrict__ agg)
{
    const int node = blockIdx.x * 4 + (threadIdx.x >> 6);
    if (node >= N_NODES) return;
    const int lane = threadIdx.x & 63;
    const int beg = row_start[node], end = row_start[node + 1];
    u16x2 mm = (u16x2)0;
    for (int base = beg; base < end; base += 16) {
        int s[16];
#pragma unroll
        for (int j = 0; j < 16; ++j) {
            const int t = base + j;
            s[j] = esrc[(t < end) ? t : beg];
        }
        unsigned int v[16];
#pragma unroll
        for (int j = 0; j < 16; ++j) v[j] = hp[(size_t)s[j] * 64 + lane];
#pragma unroll
        for (int j = 0; j < 16; ++j)
            mm = __builtin_elementwise_max(mm, __builtin_bit_cast(u16x2, v[j]));   // v_pk_max_u16
    }
    agg[(size_t)node * 64 + lane] = __builtin_bit_cast(unsigned int, mm);
}

extern "C" void kernel_launch(void* const* d_in, const int* in_sizes, int n_in,
                              void* d_out, int out_size, void* d_ws, size_t ws_size,
                              hipStream_t stream) {
    const float* node_feat = (const float*)d_in[0];
    const int* src = (const int*)d_in[1];
    const int* dst = (const int*)d_in[2];
    const float* wp[3] = {(const float*)d_in[3],  (const float*)d_in[8],  (const float*)d_in[13]};
    const float* bp[3] = {(const float*)d_in[4],  (const float*)d_in[9],  (const float*)d_in[14]};
    const float* wsm[3] = {(const float*)d_in[5], (const float*)d_in[10], (const float*)d_in[15]};
    const float* wn[3] = {(const float*)d_in[6],  (const float*)d_in[11], (const float*)d_in[16]};
    const float* bb[3] = {(const float*)d_in[7],  (const float*)d_in[12], (const float*)d_in[17]};
    const float* gamma = (const float*)d_in[18];
    const float* beta  = (const float*)d_in[19];
    const float* wc    = (const float*)d_in[20];
    const float* bc    = (const float*)d_in[21];

    const size_t SZ = (size_t)N_NODES * F;          // 12.8M elements
    short* sbase = (short*)d_ws;
    short* B0  = sbase;
    short* B1  = sbase + SZ;
    short* B2  = sbase + 2 * SZ;
    short* Xbf = sbase + 3 * SZ;
    short* wp_p  = sbase + 4 * SZ;                  // 3 × 16384
    short* wsn_p = wp_p + 3 * 16384;                // 3 × 32768
    float* fbase = (float*)(wsn_p + 3 * 32768);     // 16B-aligned
    float* stats = fbase;                           // 256
    int* ibase = (int*)(fbase + 512);
    int* deg       = ibase;                         // 100000
    int* row_start = ibase + 100000;                // 100001
    int* esrc      = ibase + 300104;                // 1000000
    int* bsum      = ibase + 1300104;               // 128
    unsigned short* erank = (unsigned short*)(ibase + 1300232);   // 1000000 u16

    const int gGemm = (N_NODES + 127) / 128;        // 782
    const int gScan = (N_NODES + 1023) / 1024;      // 98
    const int gAgg  = (N_NODES + 3) / 4;            // 25000

    // ---- zero deg + BN stats ----
    zero_misc_kernel<<<99, 256, 0, stream>>>((float4*)deg, (float4*)stats);

    // ---- convert | hist(+rank) | pack (independent, co-resident) ----
    prep_kernel<<<PREP_GROUPS * 4, 256, 0, stream>>>(
        (const float4*)node_feat, (uint2*)Xbf, dst, deg, erank,
        wp[0], wsm[0], wn[0], wp[1], wsm[1], wn[1], wp[2], wsm[2], wn[2],
        wp_p, wsn_p);

    // ---- CSR scan chain (row_start only) ----
    scan1_kernel<<<gScan, 256, 0, stream>>>(deg, bsum);
    scan2_kernel<<<1, 128, 0, stream>>>(bsum, gScan, row_start);
    scan3_kernel<<<gScan, 256, 0, stream>>>(deg, bsum, row_start);

    // ---- scatter (rank-based, no atomics) | layer-0 fc_pool GEMM: hp_0 -> B0 ----
    scatter_gemm_kernel<<<98 * 13, 256, 0, stream>>>(
        src, dst, erank, row_start, esrc,
        Xbf, wp_p, bp[0], (unsigned short*)B0);

    // ---- layer 0: agg_0 -> B1; Y_0 -> B1 (in-place over agg), hp_1 -> B0 ----
    aggregate_max_bf16<<<gAgg, 256, 0, stream>>>(
        (const unsigned int*)B0, row_start, esrc, (unsigned int*)B1);
    gemm8_fused<1><<<gGemm, 256, 0, stream>>>(
        Xbf, B1, wsn_p, bb[0], (unsigned short*)B1,
        wp_p + 16384, bp[1], (unsigned short*)B0,
        nullptr, nullptr, nullptr, nullptr, nullptr, nullptr, N_NODES, 2);

    // ---- layer 1: agg_1 -> B2; Y_1 (RAW, act=0) -> B2 (in-place) + BN stats ----
    aggregate_max_bf16<<<gAgg, 256, 0, stream>>>(
        (const unsigned int*)B0, row_start, esrc, (unsigned int*)B2);
    gemm8_fused<2><<<gGemm, 256, 0, stream>>>(
        B1, B2, wsn_p + 32768, bb[1], (unsigned short*)B2,
        nullptr, nullptr, nullptr,
        stats, nullptr, nullptr, nullptr, nullptr, nullptr, N_NODES, 0);

    // ---- layer 2 (BN prologue-RMW in consumers; bn_apply/bn_finalize deleted):
    //      hp_2 = relu(bnleaky(Y1)@Wp2+bp2) -> B0; agg_2 -> B1;
    //      Y_2 from bnleaky(Y1)@Ws + agg@Wn -> classifier -> out ----
    gemm_mfma4_bn<<<gGemm, 256, 0, stream>>>(B2,
        wp_p + 2 * 16384, bp[2], (unsigned short*)B0, N_NODES, 1,
        stats, gamma, beta);
    aggregate_max_bf16<<<gAgg, 256, 0, stream>>>(
        (const unsigned int*)B0, row_start, esrc, (unsigned int*)B1);
    gemm8_fused<3><<<gGemm, 256, 0, stream>>>(
        B2, B1, wsn_p + 2 * 32768, bb[2], nullptr,
        nullptr, nullptr, nullptr,
        stats, wc, bc, (float*)d_out, gamma, beta, N_NODES, 0);
}

// Round 13
// 499.061 us; speedup vs baseline: 1.0316x; 1.0202x over previous
//
#include <hip/hip_runtime.h>

// GraphSAGE-pool ×3 + BN + classifier, bf16 activations + MFMA GEMMs.
// R26 = R25 + __launch_bounds__(256, 4) on gemm8_fused / gemm_mfma4_bn:
//  three rounds of source-level liveness surgery (R23 reg-stage, R24 in-LDS
//  RMW, R25 prologue confinement) all left EPI3 at VGPR 160 / occ 8.3% —
//  the allocator won't go lower unless forced. min-waves/EU=4 caps VGPR at
//  128 (4 blocks/CU ceiling, was 3). RMW temps + classifier chain are in
//  confined regions, so any spill sits outside the MFMA loop.
//  All numerics bit-identical to R25 (attribute-only change).

#define N_NODES 100000
#define N_EDGES 1000000
#define F 128
#define NEG_SLOPE 0.01f
#define BN_EPS 1e-5f

typedef __attribute__((ext_vector_type(8))) short bf16x8;
typedef __attribute__((ext_vector_type(4))) float f32x4;
typedef __attribute__((ext_vector_type(2))) unsigned short u16x2;

typedef __attribute__((address_space(3))) unsigned int as3_uint;
typedef __attribute__((address_space(1))) const unsigned int as1_cuint;

__device__ __forceinline__ void gload16(const void* g, void* l) {
    __builtin_amdgcn_global_load_lds((as1_cuint*)g, (as3_uint*)l, 16, 0, 0);
}

__device__ __forceinline__ unsigned short f2bf(float f) {
    unsigned int u = __float_as_uint(f);
    u += 0x7fff + ((u >> 16) & 1);          // RNE
    return (unsigned short)(u >> 16);
}
__device__ __forceinline__ float bf2f(unsigned short h) {
    return __uint_as_float(((unsigned int)h) << 16);
}

// ---------------- combined zero fill: deg (25000 f4) + stats (64 f4) ----------------
__global__ __launch_bounds__(256) void zero_misc_kernel(
    float4* __restrict__ deg4, float4* __restrict__ stats4)
{
    if (blockIdx.x < 98) {
        const int i = blockIdx.x * 256 + threadIdx.x;
        if (i < 25000) deg4[i] = make_float4(0.f, 0.f, 0.f, 0.f);
    } else {
        if (threadIdx.x < 64) stats4[threadIdx.x] = make_float4(0.f, 0.f, 0.f, 0.f);
    }
}

// ---------------- fused prep: f32->bf16 convert | degree hist(+rank) | weight pack ----
#define PREP_GROUPS 4483
__global__ __launch_bounds__(256) void prep_kernel(
    const float4* __restrict__ nf, uint2* __restrict__ xout,
    const int* __restrict__ dst, int* __restrict__ deg,
    unsigned short* __restrict__ erank,
    const float* __restrict__ w0, const float* __restrict__ w1, const float* __restrict__ w2,
    const float* __restrict__ w3, const float* __restrict__ w4, const float* __restrict__ w5,
    const float* __restrict__ w6, const float* __restrict__ w7, const float* __restrict__ w8,
    short* __restrict__ wp_p, short* __restrict__ wsn_p)
{
    const int g = blockIdx.x >> 2;
    const int k = blockIdx.x & 3;
    const int tid = threadIdx.x;
    if (k < 3) {
        // ---- fp32 -> bf16 convert ----
        const int c = g * 3 + k;
        if (c >= 12500) return;
        const long i = (long)c * 256 + tid;
        float4 v = nf[i];
        uint2 o;
        o.x = (unsigned)f2bf(v.x) | ((unsigned)f2bf(v.y) << 16);
        o.y = (unsigned)f2bf(v.z) | ((unsigned)f2bf(v.w) << 16);
        xout[i] = o;
        return;
    }
    if (g < 3907) {
        // ---- degree histogram; keep the return = edge's rank within dst node ----
        const int e = g * 256 + tid;
        if (e < N_EDGES) {
            const int d = __builtin_nontemporal_load(&dst[e]);
            erank[e] = (unsigned short)atomicAdd(&deg[d], 1);
        }
        return;
    }
    const int po = g - 3907;
    if (po >= 576) return;
    // ---- weight pack: f32 [128][128] -> bf16 frag-order [16][128][8] ----
    const int idx = po * 256 + tid;                 // 0 .. 147455
    const int matid = idx >> 14;                    // 0..8, block-uniform
    const int layer = (matid * 11) >> 5;            // /3
    const int mat = matid - 3 * layer;
    const int i = idx & 16383;
    const int kk = i >> 7, n = i & 127;
    const float* srcm;
    switch (matid) {
        case 0: srcm = w0; break; case 1: srcm = w1; break; case 2: srcm = w2; break;
        case 3: srcm = w3; break; case 4: srcm = w4; break; case 5: srcm = w5; break;
        case 6: srcm = w6; break; case 7: srcm = w7; break; default: srcm = w8; break;
    }
    const int slot = ((kk >> 3) * 128 + n) * 8 + (kk & 7);
    const short v = (short)f2bf(srcm[i]);
    if (mat == 0) wp_p[layer * 16384 + slot] = v;
    else wsn_p[layer * 32768 + (mat == 2 ? 16384 : 0) + slot] = v;
}

// ---------------- MFMA GEMM body, m97-style (R17); BN via prologue-confined RMW ----
template<int NKS, bool BN>
__device__ __forceinline__ void gemm_body(
    const int bid,
    const short* __restrict__ A1, const short* __restrict__ A2,
    const short* __restrict__ Bp, const float* __restrict__ bias,
    unsigned short* __restrict__ Cout, const int n_rows, const int act,
    const float* __restrict__ stats, const float* __restrict__ gamma,
    const float* __restrict__ beta)
{
    constexpr int S = NKS / 2;                   // BK=64 steps
    __shared__ short tile[2 * 8192];             // 2 x (128 rows x 64 cols); reused as epilogue bounce
    __shared__ float scS[BN ? 128 : 1];
    __shared__ float sfS[BN ? 128 : 1];

    const int tid = threadIdx.x;
    const int wave = tid >> 6;
    const int lane = tid & 63;
    const int m = lane & 15, q = lane >> 4;
    const int r0 = bid * 128;
    const int rw = (wave >> 1) * 64;             // wave row-quadrant offset
    const int r0q = r0 + rw;
    const int c0 = (wave & 1) * 64;
    const int gchunk = (tid & 7) ^ ((tid >> 3) & 7);

    if constexpr (BN) {
        if (tid < 128) {
            const float inv = 1.f / N_NODES;
            const float mean = stats[tid] * inv;
            const float var = stats[128 + tid] * inv - mean * mean;
            const float sc = gamma[tid] * rsqrtf(var + BN_EPS);
            scS[tid] = sc;
            sfS[tid] = fmaf(-mean, sc, beta[tid]);
        }
    }

    f32x4 acc[4][4];
#pragma unroll
    for (int i = 0; i < 4; ++i)
#pragma unroll
        for (int j = 0; j < 4; ++j)
#pragma unroll
            for (int r = 0; r < 4; ++r) acc[i][j][r] = 0.f;

    auto stage = [&](int s, int buf) {
        const short* Ap = (NKS == 8 && s >= 2) ? A2 : A1;
        const int kbase = (s & 1) * 64;          // shorts
#pragma unroll
        for (int p = 0; p < 4; ++p) {
            int row = r0 + (tid >> 3) + 32 * p;
            row = min(row, n_rows - 1);
            gload16(Ap + (size_t)row * F + kbase + gchunk * 8,
                    &tile[buf * 8192 + p * 2048 + tid * 8]);
        }
    };

    // in-LDS BN transform of this thread's own staged slots (prologue only)
    auto rmwBN = [&](int s, int buf) {
        const int kbase = (s & 1) * 64;
        float scv[8], sfv[8];
#pragma unroll
        for (int e = 0; e < 8; ++e) {
            scv[e] = scS[kbase + gchunk * 8 + e];
            sfv[e] = sfS[kbase + gchunk * 8 + e];
        }
#pragma unroll
        for (int p = 0; p < 4; ++p) {
            unsigned int* slot = (unsigned int*)&tile[buf * 8192 + p * 2048 + tid * 8];
            const unsigned int w[4] = {slot[0], slot[1], slot[2], slot[3]};
#pragma unroll
            for (int j = 0; j < 4; ++j) {
                float lo = fmaf(bf2f((unsigned short)(w[j] & 0xffffu)), scv[2 * j], sfv[2 * j]);
                float hi = fmaf(bf2f((unsigned short)(w[j] >> 16)), scv[2 * j + 1], sfv[2 * j + 1]);
                lo = lo > 0.f ? lo : lo * NEG_SLOPE;
                hi = hi > 0.f ? hi : hi * NEG_SLOPE;
                slot[j] = (unsigned)f2bf(lo) | ((unsigned)f2bf(hi) << 16);
            }
        }
    };

    auto compute_step = [&](int s) {
        const short* tb = &tile[(s & 1) * 8192];
#pragma unroll
        for (int ks2 = 0; ks2 < 2; ++ks2) {
            const int ks32 = s * 2 + ks2;
            bf16x8 b[4], a[4];
#pragma unroll
            for (int ni = 0; ni < 4; ++ni)
                b[ni] = *(const bf16x8*)(Bp + ((size_t)(ks32 * 4 + q) * F + c0 + ni * 16 + m) * 8);
#pragma unroll
            for (int mi = 0; mi < 4; ++mi)
                a[mi] = *(const bf16x8*)(tb + (rw + mi * 16 + m) * 64 + (((ks2 * 4 + q) ^ (m & 7)) << 3));
#pragma unroll
            for (int mi = 0; mi < 4; ++mi)
#pragma unroll
                for (int ni = 0; ni < 4; ++ni)
                    acc[mi][ni] = __builtin_amdgcn_mfma_f32_16x16x32_bf16(a[mi], b[ni], acc[mi][ni], 0, 0, 0);
        }
    };

    if constexpr (BN) {
        // prologue: both Y1 halves staged + RMW'd in one region; coeffs die here
        stage(0, 0); stage(1, 1);
        __syncthreads();                         // both staged; scS/sfS visible
        rmwBN(0, 0); rmwBN(1, 1);
        __syncthreads();
        compute_step(0);
        compute_step(1);
        __syncthreads();                         // tile reads done -> epilogue alias
    } else {
        stage(0, 0);
        __syncthreads();
        for (int s = 0; s < S; ++s) {
            if (s + 1 < S) stage(s + 1, (s + 1) & 1);
            compute_step(s);
            __syncthreads();
        }
    }

    float bv[4];
#pragma unroll
    for (int ni = 0; ni < 4; ++ni) bv[ni] = bias[c0 + ni * 16 + m];

    short* ep = &tile[wave * 1280];              // aliased onto dead A-tile buffer
    const int colc_lo = m >> 3, cin = m & 7;
#pragma unroll
    for (int mi = 0; mi < 4; ++mi) {
#pragma unroll
        for (int ni = 0; ni < 4; ++ni) {
            const int colc = 2 * ni + colc_lo;
#pragma unroll
            for (int rg = 0; rg < 4; ++rg) {
                const int row16 = q * 4 + rg;
                float v = acc[mi][ni][rg] + bv[ni];
                if (act == 1) v = v > 0.f ? v : 0.f;
                else if (act == 2) v = v > 0.f ? v : v * NEG_SLOPE;
                ep[row16 * 80 + ((colc ^ (row16 & 7)) << 3) + cin] = (short)f2bf(v);
            }
        }
        __syncthreads();
#pragma unroll
        for (int p = 0; p < 2; ++p) {
            const int lrow = (lane >> 3) + 8 * p;
            bf16x8 vv = *(const bf16x8*)&ep[lrow * 80 + (((lane & 7) ^ (lrow & 7)) << 3)];
            const int grow = r0q + mi * 16 + lrow;
            if (grow < n_rows)
                *(bf16x8*)(Cout + (size_t)grow * F + c0 + ((lane & 7) << 3)) = vv;
        }
        __syncthreads();
    }
}

// layer-2 fc_pool: hp2 = relu( bnleaky(Y1) @ Wp2 + bp2 ), BN prologue RMW
__global__ __launch_bounds__(256, 4) void gemm_mfma4_bn(
    const short* __restrict__ A1,
    const short* __restrict__ Bp, const float* __restrict__ bias,
    unsigned short* __restrict__ Cout, int n_rows, int act,
    const float* __restrict__ stats, const float* __restrict__ gamma,
    const float* __restrict__ beta)
{
    gemm_body<4, true>(blockIdx.x, A1, (const short*)nullptr, Bp, bias, Cout,
                       n_rows, act, stats, gamma, beta);
}

// ---------------- fused NKS=8 Y-GEMM (R17) with per-layer tail (EPI) ----------------
// EPI=1: +hp-GEMM (Y@Bp2+bias2, relu) -> Cout2;  Y stored to Cout.
// EPI=2: +BN stats partial accumulation into stats[]; Y stored to Cout.
// EPI=3: +classifier (Ytile@Wc+bc) -> out; Y NOT stored; BN prologue RMW on A1 halves.
template<int EPI>
__global__ __launch_bounds__(256, 4) void gemm8_fused(
    const short* __restrict__ A1, const short* __restrict__ A2,
    const short* __restrict__ Bp, const float* __restrict__ bias,
    unsigned short* __restrict__ Cout,
    const short* __restrict__ Bp2, const float* __restrict__ bias2,
    unsigned short* __restrict__ Cout2,
    float* __restrict__ stats,
    const float* __restrict__ Wc, const float* __restrict__ bc,
    float* __restrict__ out,
    const float* __restrict__ gamma, const float* __restrict__ beta,
    int n_rows, int act)
{
    __shared__ short tile[2 * 8192];
    __shared__ float wcS[EPI == 3 ? 2064 : 4];   // 2048 Wc + 16 bc (EPI3 only)
    __shared__ float scS[EPI == 3 ? 128 : 1];
    __shared__ float sfS[EPI == 3 ? 128 : 1];

    const int tid = threadIdx.x;
    const int wave = tid >> 6;
    const int lane = tid & 63;
    const int m = lane & 15, q = lane >> 4;
    const int r0 = blockIdx.x * 128;
    const int rw = (wave >> 1) * 64;
    const int r0q = r0 + rw;
    const int c0 = (wave & 1) * 64;
    const int gchunk = (tid & 7) ^ ((tid >> 3) & 7);

    if constexpr (EPI == 3) {
        for (int i = tid; i < 2048; i += 256) wcS[i] = Wc[i];
        if (tid < 16) wcS[2048 + tid] = bc[tid];
        if (tid < 128) {
            const float inv = 1.f / N_NODES;
            const float mean = stats[tid] * inv;
            const float var = stats[128 + tid] * inv - mean * mean;
            const float sc = gamma[tid] * rsqrtf(var + BN_EPS);
            scS[tid] = sc;
            sfS[tid] = fmaf(-mean, sc, beta[tid]);
        }
    }

    f32x4 acc[4][4];
#pragma unroll
    for (int i = 0; i < 4; ++i)
#pragma unroll
        for (int j = 0; j < 4; ++j)
#pragma unroll
            for (int r = 0; r < 4; ++r) acc[i][j][r] = 0.f;

    auto stage = [&](int s, int buf) {
        const short* Ap = (s >= 2) ? A2 : A1;
        const int kbase = (s & 1) * 64;
#pragma unroll
        for (int p = 0; p < 4; ++p) {
            int row = r0 + (tid >> 3) + 32 * p;
            row = min(row, n_rows - 1);
            gload16(Ap + (size_t)row * F + kbase + gchunk * 8,
                    &tile[buf * 8192 + p * 2048 + tid * 8]);
        }
    };

    auto rmwBN = [&](int s, int buf) {
        const int kbase = (s & 1) * 64;
        float scv[8], sfv[8];
#pragma unroll
        for (int e = 0; e < 8; ++e) {
            scv[e] = scS[kbase + gchunk * 8 + e];
            sfv[e] = sfS[kbase + gchunk * 8 + e];
        }
#pragma unroll
        for (int p = 0; p < 4; ++p) {
            unsigned int* slot = (unsigned int*)&tile[buf * 8192 + p * 2048 + tid * 8];
            const unsigned int w[4] = {slot[0], slot[1], slot[2], slot[3]};
#pragma unroll
            for (int j = 0; j < 4; ++j) {
                float lo = fmaf(bf2f((unsigned short)(w[j] & 0xffffu)), scv[2 * j], sfv[2 * j]);
                float hi = fmaf(bf2f((unsigned short)(w[j] >> 16)), scv[2 * j + 1], sfv[2 * j + 1]);
                lo = lo > 0.f ? lo : lo * NEG_SLOPE;
                hi = hi > 0.f ? hi : hi * NEG_SLOPE;
                slot[j] = (unsigned)f2bf(lo) | ((unsigned)f2bf(hi) << 16);
            }
        }
    };

    auto compute_step = [&](const short* __restrict__ Bpp, int s, f32x4 (&ac)[4][4]) {
        const short* tb = &tile[(s & 1) * 8192];
#pragma unroll
        for (int ks2 = 0; ks2 < 2; ++ks2) {
            const int ks32 = s * 2 + ks2;
            bf16x8 b[4], a[4];
#pragma unroll
            for (int ni = 0; ni < 4; ++ni)
                b[ni] = *(const bf16x8*)(Bpp + ((size_t)(ks32 * 4 + q) * F + c0 + ni * 16 + m) * 8);
#pragma unroll
            for (int mi = 0; mi < 4; ++mi)
                a[mi] = *(const bf16x8*)(tb + (rw + mi * 16 + m) * 64 + (((ks2 * 4 + q) ^ (m & 7)) << 3));
#pragma unroll
            for (int mi = 0; mi < 4; ++mi)
#pragma unroll
                for (int ni = 0; ni < 4; ++ni)
                    ac[mi][ni] = __builtin_amdgcn_mfma_f32_16x16x32_bf16(a[mi], b[ni], ac[mi][ni], 0, 0, 0);
        }
    };

    if constexpr (EPI == 3) {
        // prologue: both Y1 halves staged + RMW'd; coeffs die before K-loop
        stage(0, 0); stage(1, 1);
        __syncthreads();                         // staged; wcS/scS/sfS visible
        rmwBN(0, 0); rmwBN(1, 1);
        __syncthreads();
        compute_step(Bp, 0, acc);
        __syncthreads();
        stage(2, 0);                             // agg half0 -> buf0
        compute_step(Bp, 1, acc);
        __syncthreads();
        stage(3, 1);                             // agg half1 -> buf1
        compute_step(Bp, 2, acc);
        __syncthreads();
        compute_step(Bp, 3, acc);
        __syncthreads();
    } else {
        stage(0, 0);
        __syncthreads();
        for (int s = 0; s < 4; ++s) {
            if (s + 1 < 4) stage(s + 1, (s + 1) & 1);
            compute_step(Bp, s, acc);
            __syncthreads();
        }
    }

    float bv[4];
#pragma unroll
    for (int ni = 0; ni < 4; ++ni) bv[ni] = bias[c0 + ni * 16 + m];

    if constexpr (EPI == 1 || EPI == 3) {
        // ---- write Y (bias+act, bf16) into the full tile in staged layout ----
        const int bufo = (wave & 1) * 8192;
#pragma unroll
        for (int mi = 0; mi < 4; ++mi)
#pragma unroll
            for (int ni = 0; ni < 4; ++ni) {
                const int chunk = ni * 2 + (m >> 3);
#pragma unroll
                for (int rg = 0; rg < 4; ++rg) {
                    const int r = rw + mi * 16 + q * 4 + rg;
                    float v = acc[mi][ni][rg] + bv[ni];
                    if (act == 1) v = v > 0.f ? v : 0.f;
                    else if (act == 2) v = v > 0.f ? v : v * NEG_SLOPE;
                    tile[bufo + r * 64 + ((chunk ^ (r & 7)) << 3) + (m & 7)] = (short)f2bf(v);
                }
            }
        __syncthreads();
    }

    if constexpr (EPI == 1) {
        // ---- store Y from tile ----
        {
            const int r = tid >> 1, half = tid & 1;
            const int grow = r0 + r;
            if (grow < n_rows) {
#pragma unroll
                for (int c = 0; c < 8; ++c) {
                    bf16x8 vv = *(const bf16x8*)&tile[half * 8192 + r * 64 + ((c ^ (r & 7)) << 3)];
                    *(bf16x8*)(Cout + (size_t)grow * F + half * 64 + c * 8) = vv;
                }
            }
        }
        // ---- hp = relu(Ytile @ Bp2 + bias2), identical schedule to gemm4 ----
        f32x4 ac2[4][4];
#pragma unroll
        for (int i = 0; i < 4; ++i)
#pragma unroll
            for (int j = 0; j < 4; ++j)
#pragma unroll
                for (int r = 0; r < 4; ++r) ac2[i][j][r] = 0.f;
        compute_step(Bp2, 0, ac2);
        compute_step(Bp2, 1, ac2);
        __syncthreads();   // all tile reads done -> safe to alias ep

        float bv2[4];
#pragma unroll
        for (int ni = 0; ni < 4; ++ni) bv2[ni] = bias2[c0 + ni * 16 + m];
        short* ep = &tile[wave * 1280];
        const int colc_lo = m >> 3, cin = m & 7;
#pragma unroll
        for (int mi = 0; mi < 4; ++mi) {
#pragma unroll
            for (int ni = 0; ni < 4; ++ni) {
                const int colc = 2 * ni + colc_lo;
#pragma unroll
                for (int rg = 0; rg < 4; ++rg) {
                    const int row16 = q * 4 + rg;
                    float v = ac2[mi][ni][rg] + bv2[ni];
                    v = v > 0.f ? v : 0.f;
                    ep[row16 * 80 + ((colc ^ (row16 & 7)) << 3) + cin] = (short)f2bf(v);
                }
            }
            __syncthreads();
#pragma unroll
            for (int p = 0; p < 2; ++p) {
                const int lrow = (lane >> 3) + 8 * p;
                bf16x8 vv = *(const bf16x8*)&ep[lrow * 80 + (((lane & 7) ^ (lrow & 7)) << 3)];
                const int grow = r0q + mi * 16 + lrow;
                if (grow < n_rows)
                    *(bf16x8*)(Cout2 + (size_t)grow * F + c0 + ((lane & 7) << 3)) = vv;
            }
            __syncthreads();
        }
    }

    if constexpr (EPI == 2) {
        // ---- BN stats partials from rounded values (+ standard Y epilogue) ----
        float* shf = (float*)&tile[8192];        // buffer1 area; ep uses buffer0 only
        {
            float s4[4] = {0.f, 0.f, 0.f, 0.f}, ss4[4] = {0.f, 0.f, 0.f, 0.f};
#pragma unroll
            for (int mi = 0; mi < 4; ++mi)
#pragma unroll
                for (int rg = 0; rg < 4; ++rg) {
                    const int grow = r0q + mi * 16 + q * 4 + rg;
                    const bool valid = grow < n_rows;
#pragma unroll
                    for (int ni = 0; ni < 4; ++ni) {
                        float v = bf2f(f2bf(acc[mi][ni][rg] + bv[ni]));  // act=0 layer
                        if (valid) { s4[ni] += v; ss4[ni] = fmaf(v, v, ss4[ni]); }
                    }
                }
#pragma unroll
            for (int ni = 0; ni < 4; ++ni) {
                s4[ni]  += __shfl_xor(s4[ni], 16);  s4[ni]  += __shfl_xor(s4[ni], 32);
                ss4[ni] += __shfl_xor(ss4[ni], 16); ss4[ni] += __shfl_xor(ss4[ni], 32);
            }
            if (lane < 16) {
#pragma unroll
                for (int ni = 0; ni < 4; ++ni) {
                    shf[wave * 128 + m * 8 + ni * 2]     = s4[ni];
                    shf[wave * 128 + m * 8 + ni * 2 + 1] = ss4[ni];
                }
            }
        }
        // standard Y epilogue (buffer0 ep); its first sync covers shf writes
        short* ep = &tile[wave * 1280];
        const int colc_lo = m >> 3, cin = m & 7;
#pragma unroll
        for (int mi = 0; mi < 4; ++mi) {
#pragma unroll
            for (int ni = 0; ni < 4; ++ni) {
                const int colc = 2 * ni + colc_lo;
#pragma unroll
                for (int rg = 0; rg < 4; ++rg) {
                    const int row16 = q * 4 + rg;
                    float v = acc[mi][ni][rg] + bv[ni];
                    if (act == 1) v = v > 0.f ? v : 0.f;
                    else if (act == 2) v = v > 0.f ? v : v * NEG_SLOPE;
                    ep[row16 * 80 + ((colc ^ (row16 & 7)) << 3) + cin] = (short)f2bf(v);
                }
            }
            __syncthreads();
#pragma unroll
            for (int p = 0; p < 2; ++p) {
                const int lrow = (lane >> 3) + 8 * p;
                bf16x8 vv = *(const bf16x8*)&ep[lrow * 80 + (((lane & 7) ^ (lrow & 7)) << 3)];
                const int grow = r0q + mi * 16 + lrow;
                if (grow < n_rows)
                    *(bf16x8*)(Cout + (size_t)grow * F + c0 + ((lane & 7) << 3)) = vv;
            }
            __syncthreads();
        }
        // combine wave pairs (0+2 cols 0-63, 1+3 cols 64-127), 256 atomics/block
        {
            const int wp = tid >> 7, m2 = (tid >> 3) & 15, j = tid & 7;
            const float val = shf[wp * 128 + m2 * 8 + j] + shf[(wp + 2) * 128 + m2 * 8 + j];
            const int col = wp * 64 + (j >> 1) * 16 + m2;
            atomicAdd(&stats[(j & 1) * 128 + col], val);
        }
    }

    if constexpr (EPI == 3) {
        // ---- classifier: out = Ytile @ Wc + bc (identical k-order fmaf chain) ----
        const int r = tid >> 1, cg = tid & 1;
        float sacc[8];
#pragma unroll
        for (int j = 0; j < 8; ++j) sacc[j] = wcS[2048 + cg * 8 + j];
#pragma unroll
        for (int k8 = 0; k8 < 16; ++k8) {
            const int buf = k8 >> 3, ch = k8 & 7;
            bf16x8 xa = *(const bf16x8*)&tile[buf * 8192 + r * 64 + ((ch ^ (r & 7)) << 3)];
#pragma unroll
            for (int e = 0; e < 8; ++e) {
                const float xv = bf2f((unsigned short)xa[e]);
                const float* wr = &wcS[(k8 * 8 + e) * 16 + cg * 8];
#pragma unroll
                for (int j = 0; j < 8; ++j) sacc[j] = fmaf(xv, wr[j], sacc[j]);
            }
        }
        const int grow = r0 + r;
        if (grow < n_rows) {
            float4 o0 = make_float4(sacc[0], sacc[1], sacc[2], sacc[3]);
            float4 o1 = make_float4(sacc[4], sacc[5], sacc[6], sacc[7]);
            *(float4*)(out + (size_t)grow * 16 + cg * 8) = o0;
            *(float4*)(out + (size_t)grow * 16 + cg * 8 + 4) = o1;
        }
    }
}

// ---------------- CSR scan (row_start only) ----------------
__global__ __launch_bounds__(256) void scan1_kernel(const int* __restrict__ deg, int* __restrict__ bsum) {
    __shared__ int sh[256];
    const int t = threadIdx.x;
    const int base = blockIdx.x * 1024 + t * 4;
    int s = 0;
#pragma unroll
    for (int j = 0; j < 4; ++j) s += (base + j < N_NODES) ? deg[base + j] : 0;
    sh[t] = s; __syncthreads();
    for (int off = 128; off; off >>= 1) {
        if (t < off) sh[t] += sh[t + off];
        __syncthreads();
    }
    if (t == 0) bsum[blockIdx.x] = sh[0];
}

__global__ __launch_bounds__(128) void scan2_kernel(int* __restrict__ bsum, int nb, int* __restrict__ row_start) {
    __shared__ int sh[128];
    const int t = threadIdx.x;
    sh[t] = (t < nb) ? bsum[t] : 0;
    __syncthreads();
    for (int off = 1; off < 128; off <<= 1) {
        int x = (t >= off) ? sh[t - off] : 0;
        __syncthreads();
        if (t >= off) sh[t] += x;
        __syncthreads();
    }
    if (t < nb) bsum[t] = t ? sh[t - 1] : 0;
    if (t == 0) row_start[N_NODES] = N_EDGES;
}

__global__ __launch_bounds__(256) void scan3_kernel(
    const int* __restrict__ deg, const int* __restrict__ boff,
    int* __restrict__ row_start)
{
    __shared__ int sh[256];
    const int t = threadIdx.x;
    const int base = blockIdx.x * 1024 + t * 4;
    int v[4]; int s = 0;
#pragma unroll
    for (int j = 0; j < 4; ++j) { v[j] = (base + j < N_NODES) ? deg[base + j] : 0; s += v[j]; }
    sh[t] = s; __syncthreads();
    for (int off = 1; off < 256; off <<= 1) {
        int x = (t >= off) ? sh[t - off] : 0;
        __syncthreads();
        if (t >= off) sh[t] += x;
        __syncthreads();
    }
    int excl = (t ? sh[t - 1] : 0) + boff[blockIdx.x];
#pragma unroll
    for (int j = 0; j < 4; ++j) {
        if (base + j < N_NODES) row_start[base + j] = excl;
        excl += v[j];
    }
}

// ---------------- fused scatter (atomic-free, rank-based) | layer-0 fc_pool GEMM ----
__global__ __launch_bounds__(256) void scatter_gemm_kernel(
    const int* __restrict__ src, const int* __restrict__ dst,
    const unsigned short* __restrict__ erank, const int* __restrict__ row_start,
    int* __restrict__ esrc,
    const short* __restrict__ A1, const short* __restrict__ Bp,
    const float* __restrict__ bias, unsigned short* __restrict__ Cout)
{
    const int bid = blockIdx.x;
    const int sgrp = bid / 13;
    const int u = bid - sgrp * 13;
    if (u < 5) {
        const int sid = sgrp * 5 + u;                // 0..489
        const int e0 = sid * 2048 + threadIdx.x;
        if (e0 >= N_EDGES) return;
        int d[8], sv[8]; int rk[8]; bool ok[8];
#pragma unroll
        for (int j = 0; j < 8; ++j) {
            const int e = e0 + j * 256;
            const int ec = min(e, N_EDGES - 1);
            ok[j] = e < N_EDGES;
            d[j] = dst[ec];
            sv[j] = src[ec];
            rk[j] = erank[ec];
        }
        int pos[8];
#pragma unroll
        for (int j = 0; j < 8; ++j) pos[j] = row_start[d[j]] + rk[j];
#pragma unroll
        for (int j = 0; j < 8; ++j)
            if (ok[j]) esrc[pos[j]] = sv[j];
    } else {
        // ---- layer-0 fc_pool GEMM (independent of CSR) ----
        const int g = sgrp * 8 + (u - 5);
        if (g >= (N_NODES + 127) / 128) return;
        gemm_body<4, false>(g, A1, (const short*)nullptr, Bp, bias, Cout,
                            N_NODES, 1, nullptr, nullptr, nullptr);
    }
}

// ---------------- aggregation: wave per node, clamped single-round gather, pk_max ----
__global__ __launch_bounds__(256) void aggregate_max_bf16(
    const unsigned int* __restrict__ hp, const int* __restrict__ row_start,
    const int* __restrict__ esrc, unsigned int* __restrict__ agg)
{
    const int node = blockIdx.x * 4 + (threadIdx.x >> 6);
    if (node >= N_NODES) return;
    const int lane = threadIdx.x & 63;
    const int beg = row_start[node], end = row_start[node + 1];
    u16x2 mm = (u16x2)0;
    for (int base = beg; base < end; base += 16) {
        int s[16];
#pragma unroll
        for (int j = 0; j < 16; ++j) {
            const int t = base + j;
            s[j] = esrc[(t < end) ? t : beg];
        }
        unsigned int v[16];
#pragma unroll
        for (int j = 0; j < 16; ++j) v[j] = hp[(size_t)s[j] * 64 + lane];
#pragma unroll
        for (int j = 0; j < 16; ++j)
            mm = __builtin_elementwise_max(mm, __builtin_bit_cast(u16x2, v[j]));   // v_pk_max_u16
    }
    agg[(size_t)node * 64 + lane] = __builtin_bit_cast(unsigned int, mm);
}

extern "C" void kernel_launch(void* const* d_in, const int* in_sizes, int n_in,
                              void* d_out, int out_size, void* d_ws, size_t ws_size,
                              hipStream_t stream) {
    const float* node_feat = (const float*)d_in[0];
    const int* src = (const int*)d_in[1];
    const int* dst = (const int*)d_in[2];
    const float* wp[3] = {(const float*)d_in[3],  (const float*)d_in[8],  (const float*)d_in[13]};
    const float* bp[3] = {(const float*)d_in[4],  (const float*)d_in[9],  (const float*)d_in[14]};
    const float* wsm[3] = {(const float*)d_in[5], (const float*)d_in[10], (const float*)d_in[15]};
    const float* wn[3] = {(const float*)d_in[6],  (const float*)d_in[11], (const float*)d_in[16]};
    const float* bb[3] = {(const float*)d_in[7],  (const float*)d_in[12], (const float*)d_in[17]};
    const float* gamma = (const float*)d_in[18];
    const float* beta  = (const float*)d_in[19];
    const float* wc    = (const float*)d_in[20];
    const float* bc    = (const float*)d_in[21];

    const size_t SZ = (size_t)N_NODES * F;          // 12.8M elements
    short* sbase = (short*)d_ws;
    short* B0  = sbase;
    short* B1  = sbase + SZ;
    short* B2  = sbase + 2 * SZ;
    short* Xbf = sbase + 3 * SZ;
    short* wp_p  = sbase + 4 * SZ;                  // 3 × 16384
    short* wsn_p = wp_p + 3 * 16384;                // 3 × 32768
    float* fbase = (float*)(wsn_p + 3 * 32768);     // 16B-aligned
    float* stats = fbase;                           // 256
    int* ibase = (int*)(fbase + 512);
    int* deg       = ibase;                         // 100000
    int* row_start = ibase + 100000;                // 100001
    int* esrc      = ibase + 300104;                // 1000000
    int* bsum      = ibase + 1300104;               // 128
    unsigned short* erank = (unsigned short*)(ibase + 1300232);   // 1000000 u16

    const int gGemm = (N_NODES + 127) / 128;        // 782
    const int gScan = (N_NODES + 1023) / 1024;      // 98
    const int gAgg  = (N_NODES + 3) / 4;            // 25000

    // ---- zero deg + BN stats ----
    zero_misc_kernel<<<99, 256, 0, stream>>>((float4*)deg, (float4*)stats);

    // ---- convert | hist(+rank) | pack (independent, co-resident) ----
    prep_kernel<<<PREP_GROUPS * 4, 256, 0, stream>>>(
        (const float4*)node_feat, (uint2*)Xbf, dst, deg, erank,
        wp[0], wsm[0], wn[0], wp[1], wsm[1], wn[1], wp[2], wsm[2], wn[2],
        wp_p, wsn_p);

    // ---- CSR scan chain (row_start only) ----
    scan1_kernel<<<gScan, 256, 0, stream>>>(deg, bsum);
    scan2_kernel<<<1, 128, 0, stream>>>(bsum, gScan, row_start);
    scan3_kernel<<<gScan, 256, 0, stream>>>(deg, bsum, row_start);

    // ---- scatter (rank-based, no atomics) | layer-0 fc_pool GEMM: hp_0 -> B0 ----
    scatter_gemm_kernel<<<98 * 13, 256, 0, stream>>>(
        src, dst, erank, row_start, esrc,
        Xbf, wp_p, bp[0], (unsigned short*)B0);

    // ---- layer 0: agg_0 -> B1; Y_0 -> B1 (in-place over agg), hp_1 -> B0 ----
    aggregate_max_bf16<<<gAgg, 256, 0, stream>>>(
        (const unsigned int*)B0, row_start, esrc, (unsigned int*)B1);
    gemm8_fused<1><<<gGemm, 256, 0, stream>>>(
        Xbf, B1, wsn_p, bb[0], (unsigned short*)B1,
        wp_p + 16384, bp[1], (unsigned short*)B0,
        nullptr, nullptr, nullptr, nullptr, nullptr, nullptr, N_NODES, 2);

    // ---- layer 1: agg_1 -> B2; Y_1 (RAW, act=0) -> B2 (in-place) + BN stats ----
    aggregate_max_bf16<<<gAgg, 256, 0, stream>>>(
        (const unsigned int*)B0, row_start, esrc, (unsigned int*)B2);
    gemm8_fused<2><<<gGemm, 256, 0, stream>>>(
        B1, B2, wsn_p + 32768, bb[1], (unsigned short*)B2,
        nullptr, nullptr, nullptr,
        stats, nullptr, nullptr, nullptr, nullptr, nullptr, N_NODES, 0);

    // ---- layer 2 (BN prologue-RMW in consumers; bn_apply/bn_finalize deleted):
    //      hp_2 = relu(bnleaky(Y1)@Wp2+bp2) -> B0; agg_2 -> B1;
    //      Y_2 from bnleaky(Y1)@Ws + agg@Wn -> classifier -> out ----
    gemm_mfma4_bn<<<gGemm, 256, 0, stream>>>(B2,
        wp_p + 2 * 16384, bp[2], (unsigned short*)B0, N_NODES, 1,
        stats, gamma, beta);
    aggregate_max_bf16<<<gAgg, 256, 0, stream>>>(
        (const unsigned int*)B0, row_start, esrc, (unsigned int*)B1);
    gemm8_fused<3><<<gGemm, 256, 0, stream>>>(
        B2, B1, wsn_p + 2 * 32768, bb[2], nullptr,
        nullptr, nullptr, nullptr,
        stats, wc, bc, (float*)d_out, gamma, beta, N_NODES, 0);
}